// Round 2
// baseline (580.008 us; speedup 1.0000x reference)
//
#include <hip/hip_runtime.h>

#define B_ 4
#define LQ 1024
#define LK 2048
#define E_ 768
#define H_ 16
#define HD_ 48
#define HDP 64

// ---- output layout (flat floats in d_out) ----
#define OUT0_SIZE (B_*LQ*E_)
#define AW_OFF    (OUT0_SIZE)
#define AW_SIZE   (B_*LQ*LK)
#define NH_OFF    (AW_OFF + AW_SIZE)
#define SF_OFF    (NH_OFF + 4)
#define GV_OFF    (NH_OFF + 8)

// ---- workspace layout (bytes) ----
#define WOFF_PIN    0
#define WOFF_QFRAG  49152                                  // [bh][LQ/16][2][64][8] bf16 (zeroed pad)
#define WOFF_KFRAG  (WOFF_QFRAG + (size_t)B_*H_*LQ*HDP*2)  // [bh][LK/16][2][64][8] bf16 (zeroed pad)
#define WOFF_VFRAG  (WOFF_KFRAG + (size_t)B_*H_*LK*HDP*2)  // [bh][LK/64][3][2][64][8] bf16
#define WOFF_CTX    (WOFF_VFRAG + (size_t)B_*H_*HD_*LK*2)  // ctx frag-major [m/16][24][64][8]
#define WOFF_DINV   (WOFF_CTX + (size_t)B_*LQ*E_*2)
#define WOFF_H1     (WOFF_DINV + (size_t)B_*H_*LQ*4)
#define WOFF_H2     (WOFF_H1 + B_*E_*4)
#define WOFF_WBF    (WOFF_H2 + B_*(E_/2)*4)                // ipw frag bf16 [144][24][64][8]
#define WOFF_OWBF   (WOFF_WBF + (size_t)2304*768*2)        // outw frag bf16 [48][24][64][8]
#define WOFF_AO     (WOFF_OWBF + (size_t)768*768*2)        // f32 [B*LQ][E]  (aliases VBF)
#define WOFF_VBF    WOFF_AO                                // value frag bf16 (dead before AO written)
#define WS_SMALL    (WOFF_AO + (size_t)B_*LQ*E_*4)
#define WOFF_QBF    WS_SMALL                               // query frag bf16
#define WOFF_KBF    (WOFF_QBF + (size_t)B_*LQ*E_*2)        // key frag bf16
#define WS_FULL     (WOFF_KBF + (size_t)B_*LK*E_*2)
#define WS_ZERO_BYTES WOFF_VFRAG

typedef unsigned short u16;
typedef __attribute__((ext_vector_type(8))) short short8;
typedef __attribute__((ext_vector_type(4))) short short4v;
typedef __attribute__((ext_vector_type(4))) float floatx4;

#define SC2 0.20823506544914194f
#define MFMA16(a,b,c) __builtin_amdgcn_mfma_f32_16x16x32_bf16(a,b,c,0,0,0)

__device__ __forceinline__ u16 f2bf(float x) {
  union { float f; unsigned u; } v; v.f = x;
  unsigned r = v.u + 0x7fffu + ((v.u >> 16) & 1u);
  return (u16)(r >> 16);
}
// HW packed f32->bf16 (RNE): 1 instr replaces ~8 ops of manual rounding+pack.
__device__ __forceinline__ unsigned cvt_pk_bf16(float a, float b) {
  unsigned r;
  asm("v_cvt_pk_bf16_f32 %0, %1, %2" : "=v"(r) : "v"(a), "v"(b));
  return r;
}
__device__ __forceinline__ short8 ldfrag_f32(const float* p) {
  const float4* q4 = (const float4*)p;
  float4 a = q4[0], b = q4[1];
  short8 r;
  r[0]=(short)f2bf(a.x); r[1]=(short)f2bf(a.y); r[2]=(short)f2bf(a.z); r[3]=(short)f2bf(a.w);
  r[4]=(short)f2bf(b.x); r[5]=(short)f2bf(b.y); r[6]=(short)f2bf(b.z); r[7]=(short)f2bf(b.w);
  return r;
}
__device__ __forceinline__ short8 ldfrag_bf16(const u16* p) { return *(const short8*)p; }

__device__ __forceinline__ size_t qkfrag_idx(int bh, int ltiles, int tile,
                                             int half, int slot, int e) {
  return ((((size_t)bh*ltiles + tile)*2 + half)*64 + slot)*8 + e;
}

// ---- f32 [R][768] row-major -> bf16 fragment-major [R/16][24][64][8] -------
__global__ __launch_bounds__(256) void conv_frag_k(const float* __restrict__ src,
                                                   u16* __restrict__ dst) {
  __shared__ u16 ls[16][776];  // +8 pad: row stride 388 dw == 4 mod 32 banks
  int tid = threadIdx.x;
  size_t base = (size_t)blockIdx.x * 16 * 768;
  #pragma unroll
  for (int j=0;j<12;j++) {
    int i4 = tid + j*256;               // 3072 float4s
    int r = i4 / 192, c4 = i4 - r*192;
    float4 v = *(const float4*)(src + base + (size_t)r*768 + c4*4);
    ushort4 o;
    o.x = f2bf(v.x); o.y = f2bf(v.y); o.z = f2bf(v.z); o.w = f2bf(v.w);
    *(ushort4*)&ls[r][c4*4] = o;
  }
  __syncthreads();
  u16* db = dst + (size_t)blockIdx.x * 24 * 512;
  #pragma unroll
  for (int j=0;j<6;j++) {
    int cid = tid + j*256;              // 1536 chunks of 8
    int kt = cid >> 6, slot = cid & 63;
    int rr = slot & 15, qq = slot >> 4;
    *(short8*)(db + (size_t)(kt*64 + slot)*8) = *(const short8*)&ls[rr][kt*32 + qq*8];
  }
}

// ---- mask -> fragment pad slots ---------------------------------------------
// qfrag pad slot d=48 := 1.0 for every q row; kfrag pad slot d=48 := -1e30 for
// masked k rows. QK^T then accumulates -1e30 into masked scores via MFMA, so
// exp2 underflows to exactly 0 -- removes all per-score mask ops from both
// attention kernels. (d=48: half=1, quad=2, e=0; other pad slots stay zero.)
__global__ __launch_bounds__(256) void maskpad_k(const unsigned char* __restrict__ mask,
    u16* __restrict__ qfrag, u16* __restrict__ kfrag) {
  int tid = blockIdx.x*256 + threadIdx.x;            // 131072 threads
  if (tid < B_*H_*LQ) {
    int bh = tid >> 10, row = tid & (LQ-1);
    qfrag[qkfrag_idx(bh, LQ/16, row>>4, 1, 32 + (row&15), 0)] = 0x3F80; // bf16(1.0)
  }
  int bh = tid >> 11, row = tid & (LK-1);
  if (mask[(size_t)(bh>>4)*LK + row])
    kfrag[qkfrag_idx(bh, LK/16, row>>4, 1, 32 + (row&15), 0)] = f2bf(-1e30f);
}

// ---------------- pooling ----------------------------------------------------
__global__ __launch_bounds__(256) void pool_k(const float* __restrict__ query,
                                              const float* __restrict__ key,
                                              float* __restrict__ pin) {
  int bid = blockIdx.x;
  const float* src; int Lrows, fofs, b, fc, lch;
  if (bid < 96) { b = bid/24; int r = bid%24; fc = r/8;  lch = r%8;  src=query; Lrows=LQ; fofs=0; }
  else { int id = bid-96; b = id/48; int r = id%48; fc = r/16; lch = r%16; src=key; Lrows=LK; fofs=E_; }
  int f = fc*256 + threadIdx.x;
  const float* p = src + ((size_t)b*Lrows + lch*128)*E_ + f;
  float s = 0.f;
  #pragma unroll 4
  for (int i=0;i<128;i++) s += p[(size_t)i*E_];
  atomicAdd(&pin[b*2*E_ + fofs + f], s);
}

// ---------------- MLP head, fp32 ---------------------------------------------
__global__ __launch_bounds__(256) void mlp1_k(const float* __restrict__ pin,
    const float* __restrict__ Wp1, const float* __restrict__ bp1,
    float* __restrict__ h1) {
  __shared__ float sp[B_][2*E_];
  int tid = threadIdx.x;
  for (int j = tid; j < B_*2*E_; j += 256) {
    int b = j / (2*E_), c = j % (2*E_);
    sp[b][c] = pin[b*2*E_ + c] * (c < E_ ? (1.f/LQ) : (1.f/LK));
  }
  __syncthreads();
  int wv = tid >> 6, lane = tid & 63;
  int rbase = (blockIdx.x*4 + wv) * 4;
  for (int rr = 0; rr < 4; rr++) {
    int r = rbase + rr;
    const float* w = Wp1 + (size_t)r*(2*E_);
    float a0=0.f,a1=0.f,a2=0.f,a3=0.f;
    for (int i = lane; i < 2*E_; i += 64) {
      float wj = w[i];
      a0 += wj*sp[0][i]; a1 += wj*sp[1][i]; a2 += wj*sp[2][i]; a3 += wj*sp[3][i];
    }
    #pragma unroll
    for (int m=1;m<64;m<<=1){
      a0+=__shfl_xor(a0,m,64); a1+=__shfl_xor(a1,m,64);
      a2+=__shfl_xor(a2,m,64); a3+=__shfl_xor(a3,m,64);
    }
    if (lane == 0) {
      float bb = bp1[r];
      h1[0*E_+r]=fmaxf(a0+bb,0.f); h1[1*E_+r]=fmaxf(a1+bb,0.f);
      h1[2*E_+r]=fmaxf(a2+bb,0.f); h1[3*E_+r]=fmaxf(a3+bb,0.f);
    }
  }
}

__global__ __launch_bounds__(256) void mlp2_k(const float* __restrict__ h1,
    const float* __restrict__ Wp2, const float* __restrict__ bp2,
    float* __restrict__ h2) {
  __shared__ float sh[B_][E_];
  int tid = threadIdx.x;
  for (int j = tid; j < B_*E_; j += 256) sh[j/E_][j%E_] = h1[j];
  __syncthreads();
  int wv = tid >> 6, lane = tid & 63;
  int rbase = (blockIdx.x*4 + wv) * 4;
  for (int rr = 0; rr < 4; rr++) {
    int r = rbase + rr;
    const float* w = Wp2 + (size_t)r*E_;
    float a0=0.f,a1=0.f,a2=0.f,a3=0.f;
    for (int i = lane; i < E_; i += 64) {
      float wj = w[i];
      a0 += wj*sh[0][i]; a1 += wj*sh[1][i]; a2 += wj*sh[2][i]; a3 += wj*sh[3][i];
    }
    #pragma unroll
    for (int m=1;m<64;m<<=1){
      a0+=__shfl_xor(a0,m,64); a1+=__shfl_xor(a1,m,64);
      a2+=__shfl_xor(a2,m,64); a3+=__shfl_xor(a3,m,64);
    }
    if (lane == 0) {
      float bb = bp2[r];
      h2[0*(E_/2)+r]=fmaxf(a0+bb,0.f); h2[1*(E_/2)+r]=fmaxf(a1+bb,0.f);
      h2[2*(E_/2)+r]=fmaxf(a2+bb,0.f); h2[3*(E_/2)+r]=fmaxf(a3+bb,0.f);
    }
  }
}

__global__ __launch_bounds__(256) void mlp3_k(const float* __restrict__ h2,
    const float* __restrict__ Wp3, const float* __restrict__ bp3,
    float* __restrict__ out) {
  int tid = threadIdx.x, wv = tid >> 6, lane = tid & 63;
  float a0=0.f,a1=0.f,a2=0.f;
  for (int i = lane; i < E_/2; i += 64) {
    float x = h2[wv*(E_/2)+i];
    a0 += x*Wp3[i]; a1 += x*Wp3[(E_/2)+i]; a2 += x*Wp3[2*(E_/2)+i];
  }
  #pragma unroll
  for (int m=1;m<64;m<<=1){
    a0+=__shfl_xor(a0,m,64); a1+=__shfl_xor(a1,m,64); a2+=__shfl_xor(a2,m,64);
  }
  if (lane == 0) {
    float p0 = a0 + bp3[0], p1 = a1 + bp3[1], p2 = a2 + bp3[2];
    float s0 = 1.f/(1.f+expf(-p0));
    float s1 = 1.f/(1.f+expf(-p1));
    float s2 = 1.f/(1.f+expf(-p2));
    out[NH_OFF + wv] = rintf(s0*(H_-1) + 1.f);
    out[SF_OFF + wv] = s1*0.5f + 0.5f;
    out[GV_OFF + wv] = s2;
  }
}

// ---- 128m x 64n GEMM, frag-major bf16 operands, XCD-chunked dispatch --------
// C[m][n] = (sum_k A[m][k]*B[n][k] + bias[n]) * cscale
// cscale folds the 1/sqrt(HD)*log2(e) softmax scale into qfrag (1.0 elsewhere).
template<int MODE, bool ABF, int TSH>
__global__ __launch_bounds__(256) void gemm_fm(const void* __restrict__ Ap,
    const u16* __restrict__ Bf, const float* __restrict__ bias,
    void* __restrict__ Cp, float cscale) {
  int lane = threadIdx.x & 63, wv = threadIdx.x >> 6;
  int lc = lane & 15, quad = lane >> 4;
  int lid = blockIdx.y * gridDim.x + blockIdx.x;
  int xcd = lid & 7, rr = lid >> 3;
  int C = gridDim.y >> 3;
  int lx = rr % gridDim.x, ly = xcd*C + rr / gridDim.x;
  int wm = ly*128 + (wv & 1)*64;
  int wn = lx*64  + (wv >> 1)*32;
  int mt0 = wm >> 4, nt0 = wn >> 4;
  const float* Af = (const float*)Ap;
  const u16*  Abf = (const u16*)Ap;
  floatx4 acc[4][2];
  #pragma unroll
  for (int s=0;s<4;s++)
    #pragma unroll
    for (int t=0;t<2;t++) acc[s][t] = (floatx4){0.f,0.f,0.f,0.f};
  #pragma unroll 2
  for (int kt=0; kt<24; kt++) {
    short8 af[4], bf2[2];
    #pragma unroll
    for (int s=0;s<4;s++)
      af[s] = ABF ? ldfrag_bf16(Abf + ((size_t)(mt0+s)*24 + kt)*512 + lane*8)
                  : ldfrag_f32(Af + (size_t)(wm + s*16 + lc)*E_ + kt*32 + quad*8);
    #pragma unroll
    for (int t=0;t<2;t++)
      bf2[t] = ldfrag_bf16(Bf + ((size_t)(nt0+t)*24 + kt)*512 + lane*8);
    #pragma unroll
    for (int s=0;s<4;s++)
      #pragma unroll
      for (int t=0;t<2;t++)
        acc[s][t] = MFMA16(af[s], bf2[t], acc[s][t]);
  }
  #pragma unroll
  for (int s=0;s<4;s++)
    #pragma unroll
    for (int t=0;t<2;t++)
      #pragma unroll
      for (int r=0;r<4;r++) {
        int m = wm + s*16 + quad*4 + r;
        int n = wn + t*16 + lc;
        float v = (acc[s][t][r] + bias[n]) * cscale;
        if (MODE == 0) {
          ((float*)Cp)[(size_t)m*E_ + n] = v;
        } else if (MODE == 1) {
          int bi = m >> TSH, l = m & ((1<<TSH)-1);
          int hh = n / HD_, d = n - hh*HD_;
          int half = d >> 5, q2 = (d >> 3) & 3, e = d & 7;
          ((u16*)Cp)[qkfrag_idx(bi*H_+hh, (1<<TSH)>>4, l>>4, half, q2*16 + (l&15), e)]
            = f2bf(v);
        } else {
          int bi = m >> 11, kc = m & 2047;
          int hh = n / HD_, d = n - hh*HD_;
          int dt = d >> 4, nn = d & 15;
          int kt2 = kc >> 6, c0 = (kc >> 5) & 1, q2 = (kc >> 3) & 3, e = kc & 7;
          size_t idx = ((((size_t)(bi*H_+hh)*(LK/64) + kt2)*3 + dt)*2 + c0)*512
                       + (q2*16+nn)*8 + e;
          ((u16*)Cp)[idx] = f2bf(v);
        }
      }
}

// ---- fused attention: 8 waves, k-split in 2 halves, LDS combine -------------
// waves 0-3: k in [0,1024), waves 4-7: k in [1024,2048) for the same 128 q rows.
// Doubles waves/SIMD (2->4) at unchanged per-block K/V cache traffic.
// Mask + softmax scale pre-folded into fragments (see maskpad_k / gemm cscale).
__global__ __launch_bounds__(512) void attn_fused_k(const u16* __restrict__ qfrag,
    const u16* __restrict__ kfrag, const u16* __restrict__ vfrag,
    float* __restrict__ dinv, u16* __restrict__ ctxb) {
  __shared__ __align__(16) u16 lp[8][16][72];
  __shared__ float cacc[4][64][33];   // stride 33: bank = lane mod 32 -> 2-way (free)
  int lane = threadIdx.x & 63, wv = threadIdx.x >> 6;
  int wq = wv & 3, kw = wv >> 2;
  int lc = lane & 15, quad = lane >> 4;
  int b = blockIdx.z, h = blockIdx.y, bh = b*H_ + h;
  int qw0 = blockIdx.x*128 + wq*32;
  const u16* qb = qfrag + (size_t)bh*(LQ/16)*1024;
  const u16* kb = kfrag + (size_t)bh*(LK/16)*1024;
  const u16* vb = vfrag + (size_t)bh*(LK/64)*3072;
  short8 qf[2][2];
  #pragma unroll
  for (int qt=0;qt<2;qt++)
    #pragma unroll
    for (int hf=0;hf<2;hf++)
      qf[qt][hf] = ldfrag_bf16(qb + (((qw0>>4)+qt)*2 + hf)*512 + lane*8);
  floatx4 lv[2];
  lv[0] = (floatx4){0.f,0.f,0.f,0.f}; lv[1] = lv[0];
  floatx4 acc[2][3];
  #pragma unroll
  for (int qt=0;qt<2;qt++)
    #pragma unroll
    for (int dt=0;dt<3;dt++) acc[qt][dt] = (floatx4){0.f,0.f,0.f,0.f};

  int kend = (kw + 1) << 10;
  for (int k0 = kw << 10; k0 < kend; k0 += 64) {
    short8 kf[4][2];
    #pragma unroll
    for (int t=0;t<4;t++)
      #pragma unroll
      for (int hf=0;hf<2;hf++)
        kf[t][hf] = ldfrag_bf16(kb + (((k0>>4)+t)*2 + hf)*512 + lane*8);
    short8 vf[2][3];
    #pragma unroll
    for (int c0=0;c0<2;c0++)
      #pragma unroll
      for (int dt=0;dt<3;dt++)
        vf[c0][dt] = ldfrag_bf16(vb + (((k0>>6)*3 + dt)*2 + c0)*512 + lane*8);

    #pragma unroll
    for (int qt=0;qt<2;qt++) {
      #pragma unroll
      for (int t=0;t<4;t++) {
        floatx4 z = {0.f,0.f,0.f,0.f};
        floatx4 st = MFMA16(kf[t][0], qf[qt][0], MFMA16(kf[t][1], qf[qt][1], z));
        floatx4 p;
        #pragma unroll
        for (int r=0;r<4;r++) p[r] = __builtin_amdgcn_exp2f(st[r]);
        lv[qt] += p;                       // 4 independent accum chains
        uint2 pk2;
        pk2.x = cvt_pk_bf16(p[0], p[1]);
        pk2.y = cvt_pk_bf16(p[2], p[3]);
        *(uint2*)&lp[wv][lc][t*16 + quad*4] = pk2;
      }
      short8 pa0 = *(const short8*)&lp[wv][lc][quad*8];
      short8 pa1 = *(const short8*)&lp[wv][lc][32 + quad*8];
      #pragma unroll
      for (int dt=0;dt<3;dt++)
        acc[qt][dt] = MFMA16(pa1, vf[1][dt], MFMA16(pa0, vf[0][dt], acc[qt][dt]));
    }
  }
  float l0 = lv[0][0]+lv[0][1]+lv[0][2]+lv[0][3];
  float l1 = lv[1][0]+lv[1][1]+lv[1][2]+lv[1][3];
  if (kw) {                               // upper half: publish partials
    float* cb = &cacc[wq][lane][0];
    #pragma unroll
    for (int qt=0;qt<2;qt++)
      #pragma unroll
      for (int dt=0;dt<3;dt++)
        #pragma unroll
        for (int r=0;r<4;r++) cb[(qt*3+dt)*4 + r] = acc[qt][dt][r];
    cb[24] = l0; cb[25] = l1;
  }
  __syncthreads();
  if (kw) return;
  {                                       // lower half: combine
    const float* cb = &cacc[wq][lane][0];
    #pragma unroll
    for (int qt=0;qt<2;qt++)
      #pragma unroll
      for (int dt=0;dt<3;dt++)
        #pragma unroll
        for (int r=0;r<4;r++) acc[qt][dt][r] += cb[(qt*3+dt)*4 + r];
    l0 += cb[24]; l1 += cb[25];
  }
  float lq[2] = {l0, l1};
  #pragma unroll
  for (int qt=0;qt<2;qt++) {
    float s = lq[qt];
    s += __shfl_xor(s, 16, 64);
    s += __shfl_xor(s, 32, 64);
    float linv = 1.f/s;
    if (lane < 16) dinv[(size_t)bh*LQ + qw0 + qt*16 + lane] = linv;
    float li[4];
    #pragma unroll
    for (int r=0;r<4;r++) li[r] = __shfl(linv, quad*4 + r, 64);
    #pragma unroll
    for (int dt=0;dt<3;dt++)
      #pragma unroll
      for (int r=0;r<4;r++) {
        int mg = b*LQ + qw0 + qt*16 + quad*4 + r;
        int k  = h*HD_ + dt*16 + lc;
        size_t idx = (((size_t)(mg>>4)*(E_/32) + (k>>5))*64 + ((k>>3)&3)*16 + (mg&15))*8 + (k&7);
        ctxb[idx] = f2bf(acc[qt][dt][r]*li[r]);
      }
  }
}

// ---- attn_weights: head loop software double-buffered, VGPR-capped ----------
// Latency-bound fix: (a) __launch_bounds__(256,4) caps VGPR at 128 -> 4
// waves/SIMD resident; (b) ping-pong fragment regs so head h+1's 8 global
// loads are in flight while head h's MFMA+exp2 chain executes.
#define AW_QSTR ((LQ/16)*1024)   // u16 elems per head in qfrag
#define AW_KSTR ((LK/16)*1024)   // u16 elems per head in kfrag

__device__ __forceinline__ void aw_load(const u16* __restrict__ qb,
    const u16* __restrict__ kb, const float* __restrict__ dv,
    int qw0, int k0, int lane, int lc,
    short8 (&qf)[2][2], short8 (&kf)[2][2], float (&di)[2]) {
  #pragma unroll
  for (int qt=0;qt<2;qt++) {
    #pragma unroll
    for (int hf=0;hf<2;hf++)
      qf[qt][hf] = ldfrag_bf16(qb + (((qw0>>4)+qt)*2 + hf)*512 + lane*8);
    di[qt] = dv[qw0 + qt*16 + lc];
  }
  #pragma unroll
  for (int t=0;t<2;t++)
    #pragma unroll
    for (int hf=0;hf<2;hf++)
      kf[t][hf] = ldfrag_bf16(kb + (((k0>>4)+t)*2 + hf)*512 + lane*8);
}

__device__ __forceinline__ void aw_compute(const short8 (&qf)[2][2],
    const short8 (&kf)[2][2], const float (&di)[2], floatx4 (&acc)[2][2]) {
  #pragma unroll
  for (int qt=0;qt<2;qt++)
    #pragma unroll
    for (int t=0;t<2;t++) {
      floatx4 z = {0.f,0.f,0.f,0.f};
      floatx4 st = MFMA16(kf[t][0], qf[qt][0], MFMA16(kf[t][1], qf[qt][1], z));
      #pragma unroll
      for (int r=0;r<4;r++)
        acc[qt][t][r] += __builtin_amdgcn_exp2f(st[r]) * di[qt];
    }
}

__global__ __launch_bounds__(256, 4) void attn_weights_k(const u16* __restrict__ qfrag,
    const u16* __restrict__ kfrag, const float* __restrict__ dinv,
    float* __restrict__ aw) {
  int lane = threadIdx.x & 63, wv = threadIdx.x >> 6;
  int lc = lane & 15, quad = lane >> 4;
  int b = blockIdx.z;
  int qw0 = blockIdx.y*64 + (wv & 1)*32;
  int k0  = blockIdx.x*64 + (wv >> 1)*32;
  const u16* qb = qfrag + (size_t)(b*H_)*AW_QSTR;
  const u16* kb = kfrag + (size_t)(b*H_)*AW_KSTR;
  const float* dv = dinv + (size_t)(b*H_)*LQ;
  floatx4 acc[2][2];
  #pragma unroll
  for (int qt=0;qt<2;qt++)
    #pragma unroll
    for (int t=0;t<2;t++) acc[qt][t] = (floatx4){0.f,0.f,0.f,0.f};
  short8 qfA[2][2], kfA[2][2], qfB[2][2], kfB[2][2];
  float diA[2], diB[2];
  aw_load(qb, kb, dv, qw0, k0, lane, lc, qfA, kfA, diA);
  #pragma unroll
  for (int h=0; h<H_; h+=2) {
    aw_load(qb + (size_t)(h+1)*AW_QSTR, kb + (size_t)(h+1)*AW_KSTR,
            dv + (size_t)(h+1)*LQ, qw0, k0, lane, lc, qfB, kfB, diB);
    aw_compute(qfA, kfA, diA, acc);
    if (h+2 < H_)
      aw_load(qb + (size_t)(h+2)*AW_QSTR, kb + (size_t)(h+2)*AW_KSTR,
              dv + (size_t)(h+2)*LQ, qw0, k0, lane, lc, qfA, kfA, diA);
    aw_compute(qfB, kfB, diB, acc);
  }
  const float inv16 = 1.f/16.f;
  #pragma unroll
  for (int qt=0;qt<2;qt++)
    #pragma unroll
    for (int t=0;t<2;t++) {
      floatx4 v = acc[qt][t];
      v[0]*=inv16; v[1]*=inv16; v[2]*=inv16; v[3]*=inv16;
      *(floatx4*)&aw[((size_t)b*LQ + qw0 + qt*16 + lc)*LK + k0 + t*16 + quad*4] = v;
    }
}

// ---------------- fused gate + residual + layernorm --------------------------
__global__ __launch_bounds__(256) void final_ln_k(const float* __restrict__ query,
    const float* __restrict__ ao, const float* __restrict__ lng,
    const float* __restrict__ lnb, float* __restrict__ out) {
  int row = blockIdx.x, b = row >> 10, tid = threadIdx.x;
  float sf = out[SF_OFF + b];
  float gv = out[GV_OFF + b];
  float c1 = 2.f - gv, c2 = sf*gv;
  const float* q = query + (size_t)row*E_;
  const float* a = ao + (size_t)row*E_;
  float x[3], s1 = 0.f, s2 = 0.f;
  #pragma unroll
  for (int i=0;i<3;i++){ int j = tid + i*256; float v = q[j]*c1 + a[j]*c2; x[i]=v; s1+=v; s2+=v*v; }
  #pragma unroll
  for (int m=1;m<64;m<<=1){ s1 += __shfl_xor(s1,m,64); s2 += __shfl_xor(s2,m,64); }
  __shared__ float r1[4], r2[4];
  int wv = tid >> 6;
  if ((tid & 63) == 0){ r1[wv]=s1; r2[wv]=s2; }
  __syncthreads();
  s1 = r1[0]+r1[1]+r1[2]+r1[3];
  s2 = r2[0]+r2[1]+r2[2]+r2[3];
  float mu = s1*(1.f/E_);
  float var = s2*(1.f/E_) - mu*mu;
  float rs = rsqrtf(var + 1e-5f);
  #pragma unroll
  for (int i=0;i<3;i++){ int j = tid + i*256; out[(size_t)row*E_ + j] = (x[i]-mu)*rs*lng[j] + lnb[j]; }
}

extern "C" void kernel_launch(void* const* d_in, const int* in_sizes, int n_in,
                              void* d_out, int out_size, void* d_ws, size_t ws_size,
                              hipStream_t stream) {
  const float* query = (const float*)d_in[0];
  const float* key   = (const float*)d_in[1];
  const float* value = (const float*)d_in[2];
  const unsigned char* mask = (const unsigned char*)d_in[3];
  const float* Wp1 = (const float*)d_in[4];
  const float* bp1 = (const float*)d_in[5];
  const float* Wp2 = (const float*)d_in[6];
  const float* bp2 = (const float*)d_in[7];
  const float* Wp3 = (const float*)d_in[8];
  const float* bp3 = (const float*)d_in[9];
  const float* ipw = (const float*)d_in[10];
  const float* ipb = (const float*)d_in[11];
  const float* outw = (const float*)d_in[12];
  const float* outb = (const float*)d_in[13];
  const float* lng = (const float*)d_in[14];
  const float* lnb = (const float*)d_in[15];
  float* out = (float*)d_out;
  char* ws = (char*)d_ws;
  if (ws_size < WS_SMALL) return;
  bool full = (ws_size >= WS_FULL);
  float* pin  = (float*)(ws + WOFF_PIN);
  u16* qfrag  = (u16*)(ws + WOFF_QFRAG);
  u16* kfrag  = (u16*)(ws + WOFF_KFRAG);
  u16* vfrag  = (u16*)(ws + WOFF_VFRAG);
  u16* ctxb   = (u16*)(ws + WOFF_CTX);
  float* dinv = (float*)(ws + WOFF_DINV);
  float* h1   = (float*)(ws + WOFF_H1);
  float* h2   = (float*)(ws + WOFF_H2);
  u16* wbf    = (u16*)(ws + WOFF_WBF);
  u16* owbf   = (u16*)(ws + WOFF_OWBF);
  float* ao   = (float*)(ws + WOFF_AO);
  u16* vbf    = (u16*)(ws + WOFF_VBF);   // aliases ao (dead before ao written)
  u16* qbf    = (u16*)(ws + WOFF_QBF);
  u16* kbf    = (u16*)(ws + WOFF_KBF);

  hipMemsetAsync(ws, 0, WS_ZERO_BYTES, stream);  // pin + q/k frag padding
  maskpad_k<<<512, 256, 0, stream>>>(mask, qfrag, kfrag);
  pool_k<<<288, 256, 0, stream>>>(query, key, pin);
  mlp1_k<<<48, 256, 0, stream>>>(pin, Wp1, bp1, h1);
  mlp2_k<<<24, 256, 0, stream>>>(h1, Wp2, bp2, h2);
  mlp3_k<<<1, 256, 0, stream>>>(h2, Wp3, bp3, out);

  conv_frag_k<<<144, 256, 0, stream>>>(ipw, wbf);
  conv_frag_k<<<48, 256, 0, stream>>>(outw, owbf);
  const u16* wq = wbf;
  const u16* wk = wbf + (size_t)48*24*512;
  const u16* wvv = wbf + (size_t)96*24*512;
  if (full) {
    conv_frag_k<<<256, 256, 0, stream>>>(query, qbf);
    conv_frag_k<<<512, 256, 0, stream>>>(key, kbf);
    conv_frag_k<<<512, 256, 0, stream>>>(value, vbf);
    gemm_fm<1,true,10><<<dim3(12,32), 256, 0, stream>>>((const void*)qbf, wq, ipb, (void*)qfrag, SC2);
    gemm_fm<1,true,11><<<dim3(12,64), 256, 0, stream>>>((const void*)kbf, wk, ipb + E_, (void*)kfrag, 1.f);
    gemm_fm<2,true,11><<<dim3(12,64), 256, 0, stream>>>((const void*)vbf, wvv, ipb + 2*E_, (void*)vfrag, 1.f);
  } else {
    gemm_fm<1,false,10><<<dim3(12,32), 256, 0, stream>>>((const void*)query, wq, ipb, (void*)qfrag, SC2);
    gemm_fm<1,false,11><<<dim3(12,64), 256, 0, stream>>>((const void*)key, wk, ipb + E_, (void*)kfrag, 1.f);
    gemm_fm<2,false,11><<<dim3(12,64), 256, 0, stream>>>((const void*)value, wvv, ipb + 2*E_, (void*)vfrag, 1.f);
  }
  attn_fused_k<<<dim3(8,16,4), 512, 0, stream>>>(qfrag, kfrag, vfrag, dinv, ctxb);
  attn_weights_k<<<dim3(32,16,4), 256, 0, stream>>>(qfrag, kfrag, dinv, out + AW_OFF);
  gemm_fm<0,true,10><<<dim3(12,32), 256, 0, stream>>>((const void*)ctxb, owbf, outb, (void*)ao, 1.f);
  final_ln_k<<<4096, 256, 0, stream>>>(query, ao, lng, lnb, out);
}

// Round 3
// 434.540 us; speedup vs baseline: 1.3348x; 1.3348x over previous
//
#include <hip/hip_runtime.h>

#define B_ 4
#define LQ 1024
#define LK 2048
#define E_ 768
#define H_ 16
#define HD_ 48
#define HDP 64

// ---- output layout (flat floats in d_out) ----
#define OUT0_SIZE (B_*LQ*E_)
#define AW_OFF    (OUT0_SIZE)
#define AW_SIZE   (B_*LQ*LK)
#define NH_OFF    (AW_OFF + AW_SIZE)
#define SF_OFF    (NH_OFF + 4)
#define GV_OFF    (NH_OFF + 8)

// ---- workspace layout (bytes) ----
#define WOFF_PIN    0
#define WOFF_QFRAG  49152                                  // [bh][LQ/16][2][64][8] bf16 (zeroed pad)
#define WOFF_KFRAG  (WOFF_QFRAG + (size_t)B_*H_*LQ*HDP*2)  // [bh][LK/16][2][64][8] bf16 (zeroed pad)
#define WOFF_VFRAG  (WOFF_KFRAG + (size_t)B_*H_*LK*HDP*2)  // [bh][LK/64][3][2][64][8] bf16
#define WOFF_CTX    (WOFF_VFRAG + (size_t)B_*H_*HD_*LK*2)  // ctx frag-major [m/16][24][64][8]
#define WOFF_DINV   (WOFF_CTX + (size_t)B_*LQ*E_*2)
#define WOFF_H1     (WOFF_DINV + (size_t)B_*H_*LQ*4)
#define WOFF_H2     (WOFF_H1 + B_*E_*4)
#define WOFF_WBF    (WOFF_H2 + B_*(E_/2)*4)                // ipw frag bf16 [144][24][64][8]
#define WOFF_OWBF   (WOFF_WBF + (size_t)2304*768*2)        // outw frag bf16 [48][24][64][8]
#define WOFF_AO     (WOFF_OWBF + (size_t)768*768*2)        // f32 [B*LQ][E]  (aliases VBF)
#define WOFF_VBF    WOFF_AO                                // value frag bf16 (dead before AO written)
#define WS_SMALL    (WOFF_AO + (size_t)B_*LQ*E_*4)
#define WOFF_QBF    WS_SMALL                               // query frag bf16
#define WOFF_KBF    (WOFF_QBF + (size_t)B_*LQ*E_*2)        // key frag bf16
#define WS_FULL     (WOFF_KBF + (size_t)B_*LK*E_*2)
#define WS_ZERO_BYTES WOFF_VFRAG

typedef unsigned short u16;
typedef __attribute__((ext_vector_type(8))) short short8;
typedef __attribute__((ext_vector_type(4))) short short4v;
typedef __attribute__((ext_vector_type(4))) float floatx4;

#define SC2 0.20823506544914194f
#define MFMA16(a,b,c) __builtin_amdgcn_mfma_f32_16x16x32_bf16(a,b,c,0,0,0)

__device__ __forceinline__ u16 f2bf(float x) {
  union { float f; unsigned u; } v; v.f = x;
  unsigned r = v.u + 0x7fffu + ((v.u >> 16) & 1u);
  return (u16)(r >> 16);
}
// HW packed f32->bf16 (RNE): 1 instr replaces ~8 ops of manual rounding+pack.
__device__ __forceinline__ unsigned cvt_pk_bf16(float a, float b) {
  unsigned r;
  asm("v_cvt_pk_bf16_f32 %0, %1, %2" : "=v"(r) : "v"(a), "v"(b));
  return r;
}
__device__ __forceinline__ short8 ldfrag_f32(const float* p) {
  const float4* q4 = (const float4*)p;
  float4 a = q4[0], b = q4[1];
  short8 r;
  r[0]=(short)f2bf(a.x); r[1]=(short)f2bf(a.y); r[2]=(short)f2bf(a.z); r[3]=(short)f2bf(a.w);
  r[4]=(short)f2bf(b.x); r[5]=(short)f2bf(b.y); r[6]=(short)f2bf(b.z); r[7]=(short)f2bf(b.w);
  return r;
}
__device__ __forceinline__ short8 ldfrag_bf16(const u16* p) { return *(const short8*)p; }

__device__ __forceinline__ size_t qkfrag_idx(int bh, int ltiles, int tile,
                                             int half, int slot, int e) {
  return ((((size_t)bh*ltiles + tile)*2 + half)*64 + slot)*8 + e;
}

// ---- f32 [R][768] row-major -> bf16 fragment-major [R/16][24][64][8] -------
__global__ __launch_bounds__(256) void conv_frag_k(const float* __restrict__ src,
                                                   u16* __restrict__ dst) {
  __shared__ u16 ls[16][776];  // +8 pad: row stride 388 dw == 4 mod 32 banks
  int tid = threadIdx.x;
  size_t base = (size_t)blockIdx.x * 16 * 768;
  #pragma unroll
  for (int j=0;j<12;j++) {
    int i4 = tid + j*256;               // 3072 float4s
    int r = i4 / 192, c4 = i4 - r*192;
    float4 v = *(const float4*)(src + base + (size_t)r*768 + c4*4);
    ushort4 o;
    o.x = f2bf(v.x); o.y = f2bf(v.y); o.z = f2bf(v.z); o.w = f2bf(v.w);
    *(ushort4*)&ls[r][c4*4] = o;
  }
  __syncthreads();
  u16* db = dst + (size_t)blockIdx.x * 24 * 512;
  #pragma unroll
  for (int j=0;j<6;j++) {
    int cid = tid + j*256;              // 1536 chunks of 8
    int kt = cid >> 6, slot = cid & 63;
    int rr = slot & 15, qq = slot >> 4;
    *(short8*)(db + (size_t)(kt*64 + slot)*8) = *(const short8*)&ls[rr][kt*32 + qq*8];
  }
}

// ---- mask -> fragment pad slots ---------------------------------------------
// qfrag pad slot d=48 := 1.0 for every q row; kfrag pad slot d=48 := -1e30 for
// masked k rows. QK^T then accumulates -1e30 into masked scores via MFMA, so
// exp2 underflows to exactly 0 -- removes all per-score mask ops from both
// attention kernels. (d=48: half=1, quad=2, e=0; other pad slots stay zero.)
__global__ __launch_bounds__(256) void maskpad_k(const unsigned char* __restrict__ mask,
    u16* __restrict__ qfrag, u16* __restrict__ kfrag) {
  int tid = blockIdx.x*256 + threadIdx.x;            // 131072 threads
  if (tid < B_*H_*LQ) {
    int bh = tid >> 10, row = tid & (LQ-1);
    qfrag[qkfrag_idx(bh, LQ/16, row>>4, 1, 32 + (row&15), 0)] = 0x3F80; // bf16(1.0)
  }
  int bh = tid >> 11, row = tid & (LK-1);
  if (mask[(size_t)(bh>>4)*LK + row])
    kfrag[qkfrag_idx(bh, LK/16, row>>4, 1, 32 + (row&15), 0)] = f2bf(-1e30f);
}

// ---------------- pooling ----------------------------------------------------
__global__ __launch_bounds__(256) void pool_k(const float* __restrict__ query,
                                              const float* __restrict__ key,
                                              float* __restrict__ pin) {
  int bid = blockIdx.x;
  const float* src; int Lrows, fofs, b, fc, lch;
  if (bid < 96) { b = bid/24; int r = bid%24; fc = r/8;  lch = r%8;  src=query; Lrows=LQ; fofs=0; }
  else { int id = bid-96; b = id/48; int r = id%48; fc = r/16; lch = r%16; src=key; Lrows=LK; fofs=E_; }
  int f = fc*256 + threadIdx.x;
  const float* p = src + ((size_t)b*Lrows + lch*128)*E_ + f;
  float s = 0.f;
  #pragma unroll 4
  for (int i=0;i<128;i++) s += p[(size_t)i*E_];
  atomicAdd(&pin[b*2*E_ + fofs + f], s);
}

// ---------------- MLP head, fp32 ---------------------------------------------
__global__ __launch_bounds__(256) void mlp1_k(const float* __restrict__ pin,
    const float* __restrict__ Wp1, const float* __restrict__ bp1,
    float* __restrict__ h1) {
  __shared__ float sp[B_][2*E_];
  int tid = threadIdx.x;
  for (int j = tid; j < B_*2*E_; j += 256) {
    int b = j / (2*E_), c = j % (2*E_);
    sp[b][c] = pin[b*2*E_ + c] * (c < E_ ? (1.f/LQ) : (1.f/LK));
  }
  __syncthreads();
  int wv = tid >> 6, lane = tid & 63;
  int rbase = (blockIdx.x*4 + wv) * 4;
  for (int rr = 0; rr < 4; rr++) {
    int r = rbase + rr;
    const float* w = Wp1 + (size_t)r*(2*E_);
    float a0=0.f,a1=0.f,a2=0.f,a3=0.f;
    for (int i = lane; i < 2*E_; i += 64) {
      float wj = w[i];
      a0 += wj*sp[0][i]; a1 += wj*sp[1][i]; a2 += wj*sp[2][i]; a3 += wj*sp[3][i];
    }
    #pragma unroll
    for (int m=1;m<64;m<<=1){
      a0+=__shfl_xor(a0,m,64); a1+=__shfl_xor(a1,m,64);
      a2+=__shfl_xor(a2,m,64); a3+=__shfl_xor(a3,m,64);
    }
    if (lane == 0) {
      float bb = bp1[r];
      h1[0*E_+r]=fmaxf(a0+bb,0.f); h1[1*E_+r]=fmaxf(a1+bb,0.f);
      h1[2*E_+r]=fmaxf(a2+bb,0.f); h1[3*E_+r]=fmaxf(a3+bb,0.f);
    }
  }
}

__global__ __launch_bounds__(256) void mlp2_k(const float* __restrict__ h1,
    const float* __restrict__ Wp2, const float* __restrict__ bp2,
    float* __restrict__ h2) {
  __shared__ float sh[B_][E_];
  int tid = threadIdx.x;
  for (int j = tid; j < B_*E_; j += 256) sh[j/E_][j%E_] = h1[j];
  __syncthreads();
  int wv = tid >> 6, lane = tid & 63;
  int rbase = (blockIdx.x*4 + wv) * 4;
  for (int rr = 0; rr < 4; rr++) {
    int r = rbase + rr;
    const float* w = Wp2 + (size_t)r*E_;
    float a0=0.f,a1=0.f,a2=0.f,a3=0.f;
    for (int i = lane; i < E_; i += 64) {
      float wj = w[i];
      a0 += wj*sh[0][i]; a1 += wj*sh[1][i]; a2 += wj*sh[2][i]; a3 += wj*sh[3][i];
    }
    #pragma unroll
    for (int m=1;m<64;m<<=1){
      a0+=__shfl_xor(a0,m,64); a1+=__shfl_xor(a1,m,64);
      a2+=__shfl_xor(a2,m,64); a3+=__shfl_xor(a3,m,64);
    }
    if (lane == 0) {
      float bb = bp2[r];
      h2[0*(E_/2)+r]=fmaxf(a0+bb,0.f); h2[1*(E_/2)+r]=fmaxf(a1+bb,0.f);
      h2[2*(E_/2)+r]=fmaxf(a2+bb,0.f); h2[3*(E_/2)+r]=fmaxf(a3+bb,0.f);
    }
  }
}

__global__ __launch_bounds__(256) void mlp3_k(const float* __restrict__ h2,
    const float* __restrict__ Wp3, const float* __restrict__ bp3,
    float* __restrict__ out) {
  int tid = threadIdx.x, wv = tid >> 6, lane = tid & 63;
  float a0=0.f,a1=0.f,a2=0.f;
  for (int i = lane; i < E_/2; i += 64) {
    float x = h2[wv*(E_/2)+i];
    a0 += x*Wp3[i]; a1 += x*Wp3[(E_/2)+i]; a2 += x*Wp3[2*(E_/2)+i];
  }
  #pragma unroll
  for (int m=1;m<64;m<<=1){
    a0+=__shfl_xor(a0,m,64); a1+=__shfl_xor(a1,m,64); a2+=__shfl_xor(a2,m,64);
  }
  if (lane == 0) {
    float p0 = a0 + bp3[0], p1 = a1 + bp3[1], p2 = a2 + bp3[2];
    float s0 = 1.f/(1.f+expf(-p0));
    float s1 = 1.f/(1.f+expf(-p1));
    float s2 = 1.f/(1.f+expf(-p2));
    out[NH_OFF + wv] = rintf(s0*(H_-1) + 1.f);
    out[SF_OFF + wv] = s1*0.5f + 0.5f;
    out[GV_OFF + wv] = s2;
  }
}

// ---- 128m x 64n GEMM, frag-major bf16 operands, XCD-chunked dispatch --------
// C[m][n] = (sum_k A[m][k]*B[n][k] + bias[n]) * cscale
// cscale folds the 1/sqrt(HD)*log2(e) softmax scale into qfrag (1.0 elsewhere).
template<int MODE, bool ABF, int TSH>
__global__ __launch_bounds__(256) void gemm_fm(const void* __restrict__ Ap,
    const u16* __restrict__ Bf, const float* __restrict__ bias,
    void* __restrict__ Cp, float cscale) {
  int lane = threadIdx.x & 63, wv = threadIdx.x >> 6;
  int lc = lane & 15, quad = lane >> 4;
  int lid = blockIdx.y * gridDim.x + blockIdx.x;
  int xcd = lid & 7, rr = lid >> 3;
  int C = gridDim.y >> 3;
  int lx = rr % gridDim.x, ly = xcd*C + rr / gridDim.x;
  int wm = ly*128 + (wv & 1)*64;
  int wn = lx*64  + (wv >> 1)*32;
  int mt0 = wm >> 4, nt0 = wn >> 4;
  const float* Af = (const float*)Ap;
  const u16*  Abf = (const u16*)Ap;
  floatx4 acc[4][2];
  #pragma unroll
  for (int s=0;s<4;s++)
    #pragma unroll
    for (int t=0;t<2;t++) acc[s][t] = (floatx4){0.f,0.f,0.f,0.f};
  #pragma unroll 2
  for (int kt=0; kt<24; kt++) {
    short8 af[4], bf2[2];
    #pragma unroll
    for (int s=0;s<4;s++)
      af[s] = ABF ? ldfrag_bf16(Abf + ((size_t)(mt0+s)*24 + kt)*512 + lane*8)
                  : ldfrag_f32(Af + (size_t)(wm + s*16 + lc)*E_ + kt*32 + quad*8);
    #pragma unroll
    for (int t=0;t<2;t++)
      bf2[t] = ldfrag_bf16(Bf + ((size_t)(nt0+t)*24 + kt)*512 + lane*8);
    #pragma unroll
    for (int s=0;s<4;s++)
      #pragma unroll
      for (int t=0;t<2;t++)
        acc[s][t] = MFMA16(af[s], bf2[t], acc[s][t]);
  }
  #pragma unroll
  for (int s=0;s<4;s++)
    #pragma unroll
    for (int t=0;t<2;t++)
      #pragma unroll
      for (int r=0;r<4;r++) {
        int m = wm + s*16 + quad*4 + r;
        int n = wn + t*16 + lc;
        float v = (acc[s][t][r] + bias[n]) * cscale;
        if (MODE == 0) {
          ((float*)Cp)[(size_t)m*E_ + n] = v;
        } else if (MODE == 1) {
          int bi = m >> TSH, l = m & ((1<<TSH)-1);
          int hh = n / HD_, d = n - hh*HD_;
          int half = d >> 5, q2 = (d >> 3) & 3, e = d & 7;
          ((u16*)Cp)[qkfrag_idx(bi*H_+hh, (1<<TSH)>>4, l>>4, half, q2*16 + (l&15), e)]
            = f2bf(v);
        } else {
          int bi = m >> 11, kc = m & 2047;
          int hh = n / HD_, d = n - hh*HD_;
          int dt = d >> 4, nn = d & 15;
          int kt2 = kc >> 6, c0 = (kc >> 5) & 1, q2 = (kc >> 3) & 3, e = kc & 7;
          size_t idx = ((((size_t)(bi*H_+hh)*(LK/64) + kt2)*3 + dt)*2 + c0)*512
                       + (q2*16+nn)*8 + e;
          ((u16*)Cp)[idx] = f2bf(v);
        }
      }
}

// ---- fused attention: 8 waves, k-split in 2 halves, LDS combine -------------
// waves 0-3: k in [0,1024), waves 4-7: k in [1024,2048) for the same 128 q rows.
// Doubles waves/SIMD (2->4) at unchanged per-block K/V cache traffic.
// Mask + softmax scale pre-folded into fragments (see maskpad_k / gemm cscale).
__global__ __launch_bounds__(512) void attn_fused_k(const u16* __restrict__ qfrag,
    const u16* __restrict__ kfrag, const u16* __restrict__ vfrag,
    float* __restrict__ dinv, u16* __restrict__ ctxb) {
  __shared__ __align__(16) u16 lp[8][16][72];
  __shared__ float cacc[4][64][33];   // stride 33: bank = lane mod 32 -> 2-way (free)
  int lane = threadIdx.x & 63, wv = threadIdx.x >> 6;
  int wq = wv & 3, kw = wv >> 2;
  int lc = lane & 15, quad = lane >> 4;
  int b = blockIdx.z, h = blockIdx.y, bh = b*H_ + h;
  int qw0 = blockIdx.x*128 + wq*32;
  const u16* qb = qfrag + (size_t)bh*(LQ/16)*1024;
  const u16* kb = kfrag + (size_t)bh*(LK/16)*1024;
  const u16* vb = vfrag + (size_t)bh*(LK/64)*3072;
  short8 qf[2][2];
  #pragma unroll
  for (int qt=0;qt<2;qt++)
    #pragma unroll
    for (int hf=0;hf<2;hf++)
      qf[qt][hf] = ldfrag_bf16(qb + (((qw0>>4)+qt)*2 + hf)*512 + lane*8);
  floatx4 lv[2];
  lv[0] = (floatx4){0.f,0.f,0.f,0.f}; lv[1] = lv[0];
  floatx4 acc[2][3];
  #pragma unroll
  for (int qt=0;qt<2;qt++)
    #pragma unroll
    for (int dt=0;dt<3;dt++) acc[qt][dt] = (floatx4){0.f,0.f,0.f,0.f};

  int kend = (kw + 1) << 10;
  for (int k0 = kw << 10; k0 < kend; k0 += 64) {
    short8 kf[4][2];
    #pragma unroll
    for (int t=0;t<4;t++)
      #pragma unroll
      for (int hf=0;hf<2;hf++)
        kf[t][hf] = ldfrag_bf16(kb + (((k0>>4)+t)*2 + hf)*512 + lane*8);
    short8 vf[2][3];
    #pragma unroll
    for (int c0=0;c0<2;c0++)
      #pragma unroll
      for (int dt=0;dt<3;dt++)
        vf[c0][dt] = ldfrag_bf16(vb + (((k0>>6)*3 + dt)*2 + c0)*512 + lane*8);

    #pragma unroll
    for (int qt=0;qt<2;qt++) {
      #pragma unroll
      for (int t=0;t<4;t++) {
        floatx4 z = {0.f,0.f,0.f,0.f};
        floatx4 st = MFMA16(kf[t][0], qf[qt][0], MFMA16(kf[t][1], qf[qt][1], z));
        floatx4 p;
        #pragma unroll
        for (int r=0;r<4;r++) p[r] = __builtin_amdgcn_exp2f(st[r]);
        lv[qt] += p;                       // 4 independent accum chains
        uint2 pk2;
        pk2.x = cvt_pk_bf16(p[0], p[1]);
        pk2.y = cvt_pk_bf16(p[2], p[3]);
        *(uint2*)&lp[wv][lc][t*16 + quad*4] = pk2;
      }
      short8 pa0 = *(const short8*)&lp[wv][lc][quad*8];
      short8 pa1 = *(const short8*)&lp[wv][lc][32 + quad*8];
      #pragma unroll
      for (int dt=0;dt<3;dt++)
        acc[qt][dt] = MFMA16(pa1, vf[1][dt], MFMA16(pa0, vf[0][dt], acc[qt][dt]));
    }
  }
  float l0 = lv[0][0]+lv[0][1]+lv[0][2]+lv[0][3];
  float l1 = lv[1][0]+lv[1][1]+lv[1][2]+lv[1][3];
  if (kw) {                               // upper half: publish partials
    float* cb = &cacc[wq][lane][0];
    #pragma unroll
    for (int qt=0;qt<2;qt++)
      #pragma unroll
      for (int dt=0;dt<3;dt++)
        #pragma unroll
        for (int r=0;r<4;r++) cb[(qt*3+dt)*4 + r] = acc[qt][dt][r];
    cb[24] = l0; cb[25] = l1;
  }
  __syncthreads();
  if (kw) return;
  {                                       // lower half: combine
    const float* cb = &cacc[wq][lane][0];
    #pragma unroll
    for (int qt=0;qt<2;qt++)
      #pragma unroll
      for (int dt=0;dt<3;dt++)
        #pragma unroll
        for (int r=0;r<4;r++) acc[qt][dt][r] += cb[(qt*3+dt)*4 + r];
    l0 += cb[24]; l1 += cb[25];
  }
  float lq[2] = {l0, l1};
  #pragma unroll
  for (int qt=0;qt<2;qt++) {
    float s = lq[qt];
    s += __shfl_xor(s, 16, 64);
    s += __shfl_xor(s, 32, 64);
    float linv = 1.f/s;
    if (lane < 16) dinv[(size_t)bh*LQ + qw0 + qt*16 + lane] = linv;
    float li[4];
    #pragma unroll
    for (int r=0;r<4;r++) li[r] = __shfl(linv, quad*4 + r, 64);
    #pragma unroll
    for (int dt=0;dt<3;dt++)
      #pragma unroll
      for (int r=0;r<4;r++) {
        int mg = b*LQ + qw0 + qt*16 + quad*4 + r;
        int k  = h*HD_ + dt*16 + lc;
        size_t idx = (((size_t)(mg>>4)*(E_/32) + (k>>5))*64 + ((k>>3)&3)*16 + (mg&15))*8 + (k&7);
        ctxb[idx] = f2bf(acc[qt][dt][r]*li[r]);
      }
  }
}

// ---- attn_weights: head loop software double-buffered, NO occupancy cap -----
// R2 lesson: __launch_bounds__(256,4) forced a 128-reg unified budget -> 64
// arch VGPR + massive scratch spills (FETCH 42->249MB, WRITE 33->407MB).
// Same ping-pong structure, uncapped: ~170 VGPR stays in the 2-waves/SIMD bin
// (same residency as R1's 140) but head h+1's loads overlap head h's compute.
#define AW_QSTR ((LQ/16)*1024)   // u16 elems per head in qfrag
#define AW_KSTR ((LK/16)*1024)   // u16 elems per head in kfrag

__device__ __forceinline__ void aw_load(const u16* __restrict__ qb,
    const u16* __restrict__ kb, const float* __restrict__ dv,
    int qw0, int k0, int lane, int lc,
    short8 (&qf)[2][2], short8 (&kf)[2][2], float (&di)[2]) {
  #pragma unroll
  for (int qt=0;qt<2;qt++) {
    #pragma unroll
    for (int hf=0;hf<2;hf++)
      qf[qt][hf] = ldfrag_bf16(qb + (((qw0>>4)+qt)*2 + hf)*512 + lane*8);
    di[qt] = dv[qw0 + qt*16 + lc];
  }
  #pragma unroll
  for (int t=0;t<2;t++)
    #pragma unroll
    for (int hf=0;hf<2;hf++)
      kf[t][hf] = ldfrag_bf16(kb + (((k0>>4)+t)*2 + hf)*512 + lane*8);
}

__device__ __forceinline__ void aw_compute(const short8 (&qf)[2][2],
    const short8 (&kf)[2][2], const float (&di)[2], floatx4 (&acc)[2][2]) {
  #pragma unroll
  for (int qt=0;qt<2;qt++)
    #pragma unroll
    for (int t=0;t<2;t++) {
      floatx4 z = {0.f,0.f,0.f,0.f};
      floatx4 st = MFMA16(kf[t][0], qf[qt][0], MFMA16(kf[t][1], qf[qt][1], z));
      #pragma unroll
      for (int r=0;r<4;r++)
        acc[qt][t][r] += __builtin_amdgcn_exp2f(st[r]) * di[qt];
    }
}

__global__ __launch_bounds__(256) void attn_weights_k(const u16* __restrict__ qfrag,
    const u16* __restrict__ kfrag, const float* __restrict__ dinv,
    float* __restrict__ aw) {
  int lane = threadIdx.x & 63, wv = threadIdx.x >> 6;
  int lc = lane & 15, quad = lane >> 4;
  int b = blockIdx.z;
  int qw0 = blockIdx.y*64 + (wv & 1)*32;
  int k0  = blockIdx.x*64 + (wv >> 1)*32;
  const u16* qb = qfrag + (size_t)(b*H_)*AW_QSTR;
  const u16* kb = kfrag + (size_t)(b*H_)*AW_KSTR;
  const float* dv = dinv + (size_t)(b*H_)*LQ;
  floatx4 acc[2][2];
  #pragma unroll
  for (int qt=0;qt<2;qt++)
    #pragma unroll
    for (int t=0;t<2;t++) acc[qt][t] = (floatx4){0.f,0.f,0.f,0.f};
  short8 qfA[2][2], kfA[2][2], qfB[2][2], kfB[2][2];
  float diA[2], diB[2];
  aw_load(qb, kb, dv, qw0, k0, lane, lc, qfA, kfA, diA);
  #pragma unroll
  for (int h=0; h<H_; h+=2) {
    aw_load(qb + (size_t)(h+1)*AW_QSTR, kb + (size_t)(h+1)*AW_KSTR,
            dv + (size_t)(h+1)*LQ, qw0, k0, lane, lc, qfB, kfB, diB);
    aw_compute(qfA, kfA, diA, acc);
    if (h+2 < H_)
      aw_load(qb + (size_t)(h+2)*AW_QSTR, kb + (size_t)(h+2)*AW_KSTR,
              dv + (size_t)(h+2)*LQ, qw0, k0, lane, lc, qfA, kfA, diA);
    aw_compute(qfB, kfB, diB, acc);
  }
  const float inv16 = 1.f/16.f;
  #pragma unroll
  for (int qt=0;qt<2;qt++)
    #pragma unroll
    for (int t=0;t<2;t++) {
      floatx4 v = acc[qt][t];
      v[0]*=inv16; v[1]*=inv16; v[2]*=inv16; v[3]*=inv16;
      *(floatx4*)&aw[((size_t)b*LQ + qw0 + qt*16 + lc)*LK + k0 + t*16 + quad*4] = v;
    }
}

// ---------------- fused gate + residual + layernorm --------------------------
__global__ __launch_bounds__(256) void final_ln_k(const float* __restrict__ query,
    const float* __restrict__ ao, const float* __restrict__ lng,
    const float* __restrict__ lnb, float* __restrict__ out) {
  int row = blockIdx.x, b = row >> 10, tid = threadIdx.x;
  float sf = out[SF_OFF + b];
  float gv = out[GV_OFF + b];
  float c1 = 2.f - gv, c2 = sf*gv;
  const float* q = query + (size_t)row*E_;
  const float* a = ao + (size_t)row*E_;
  float x[3], s1 = 0.f, s2 = 0.f;
  #pragma unroll
  for (int i=0;i<3;i++){ int j = tid + i*256; float v = q[j]*c1 + a[j]*c2; x[i]=v; s1+=v; s2+=v*v; }
  #pragma unroll
  for (int m=1;m<64;m<<=1){ s1 += __shfl_xor(s1,m,64); s2 += __shfl_xor(s2,m,64); }
  __shared__ float r1[4], r2[4];
  int wv = tid >> 6;
  if ((tid & 63) == 0){ r1[wv]=s1; r2[wv]=s2; }
  __syncthreads();
  s1 = r1[0]+r1[1]+r1[2]+r1[3];
  s2 = r2[0]+r2[1]+r2[2]+r2[3];
  float mu = s1*(1.f/E_);
  float var = s2*(1.f/E_) - mu*mu;
  float rs = rsqrtf(var + 1e-5f);
  #pragma unroll
  for (int i=0;i<3;i++){ int j = tid + i*256; out[(size_t)row*E_ + j] = (x[i]-mu)*rs*lng[j] + lnb[j]; }
}

extern "C" void kernel_launch(void* const* d_in, const int* in_sizes, int n_in,
                              void* d_out, int out_size, void* d_ws, size_t ws_size,
                              hipStream_t stream) {
  const float* query = (const float*)d_in[0];
  const float* key   = (const float*)d_in[1];
  const float* value = (const float*)d_in[2];
  const unsigned char* mask = (const unsigned char*)d_in[3];
  const float* Wp1 = (const float*)d_in[4];
  const float* bp1 = (const float*)d_in[5];
  const float* Wp2 = (const float*)d_in[6];
  const float* bp2 = (const float*)d_in[7];
  const float* Wp3 = (const float*)d_in[8];
  const float* bp3 = (const float*)d_in[9];
  const float* ipw = (const float*)d_in[10];
  const float* ipb = (const float*)d_in[11];
  const float* outw = (const float*)d_in[12];
  const float* outb = (const float*)d_in[13];
  const float* lng = (const float*)d_in[14];
  const float* lnb = (const float*)d_in[15];
  float* out = (float*)d_out;
  char* ws = (char*)d_ws;
  if (ws_size < WS_SMALL) return;
  bool full = (ws_size >= WS_FULL);
  float* pin  = (float*)(ws + WOFF_PIN);
  u16* qfrag  = (u16*)(ws + WOFF_QFRAG);
  u16* kfrag  = (u16*)(ws + WOFF_KFRAG);
  u16* vfrag  = (u16*)(ws + WOFF_VFRAG);
  u16* ctxb   = (u16*)(ws + WOFF_CTX);
  float* dinv = (float*)(ws + WOFF_DINV);
  float* h1   = (float*)(ws + WOFF_H1);
  float* h2   = (float*)(ws + WOFF_H2);
  u16* wbf    = (u16*)(ws + WOFF_WBF);
  u16* owbf   = (u16*)(ws + WOFF_OWBF);
  float* ao   = (float*)(ws + WOFF_AO);
  u16* vbf    = (u16*)(ws + WOFF_VBF);   // aliases ao (dead before ao written)
  u16* qbf    = (u16*)(ws + WOFF_QBF);
  u16* kbf    = (u16*)(ws + WOFF_KBF);

  hipMemsetAsync(ws, 0, WS_ZERO_BYTES, stream);  // pin + q/k frag padding
  maskpad_k<<<512, 256, 0, stream>>>(mask, qfrag, kfrag);
  pool_k<<<288, 256, 0, stream>>>(query, key, pin);
  mlp1_k<<<48, 256, 0, stream>>>(pin, Wp1, bp1, h1);
  mlp2_k<<<24, 256, 0, stream>>>(h1, Wp2, bp2, h2);
  mlp3_k<<<1, 256, 0, stream>>>(h2, Wp3, bp3, out);

  conv_frag_k<<<144, 256, 0, stream>>>(ipw, wbf);
  conv_frag_k<<<48, 256, 0, stream>>>(outw, owbf);
  const u16* wq = wbf;
  const u16* wk = wbf + (size_t)48*24*512;
  const u16* wvv = wbf + (size_t)96*24*512;
  if (full) {
    conv_frag_k<<<256, 256, 0, stream>>>(query, qbf);
    conv_frag_k<<<512, 256, 0, stream>>>(key, kbf);
    conv_frag_k<<<512, 256, 0, stream>>>(value, vbf);
    gemm_fm<1,true,10><<<dim3(12,32), 256, 0, stream>>>((const void*)qbf, wq, ipb, (void*)qfrag, SC2);
    gemm_fm<1,true,11><<<dim3(12,64), 256, 0, stream>>>((const void*)kbf, wk, ipb + E_, (void*)kfrag, 1.f);
    gemm_fm<2,true,11><<<dim3(12,64), 256, 0, stream>>>((const void*)vbf, wvv, ipb + 2*E_, (void*)vfrag, 1.f);
  } else {
    gemm_fm<1,false,10><<<dim3(12,32), 256, 0, stream>>>((const void*)query, wq, ipb, (void*)qfrag, SC2);
    gemm_fm<1,false,11><<<dim3(12,64), 256, 0, stream>>>((const void*)key, wk, ipb + E_, (void*)kfrag, 1.f);
    gemm_fm<2,false,11><<<dim3(12,64), 256, 0, stream>>>((const void*)value, wvv, ipb + 2*E_, (void*)vfrag, 1.f);
  }
  attn_fused_k<<<dim3(8,16,4), 512, 0, stream>>>(qfrag, kfrag, vfrag, dinv, ctxb);
  attn_weights_k<<<dim3(32,16,4), 256, 0, stream>>>(qfrag, kfrag, dinv, out + AW_OFF);
  gemm_fm<0,true,10><<<dim3(12,32), 256, 0, stream>>>((const void*)ctxb, owbf, outb, (void*)ao, 1.f);
  final_ln_k<<<4096, 256, 0, stream>>>(query, ao, lng, lnb, out);
}

// Round 4
// 406.862 us; speedup vs baseline: 1.4256x; 1.0680x over previous
//
#include <hip/hip_runtime.h>

#define B_ 4
#define LQ 1024
#define LK 2048
#define E_ 768
#define H_ 16
#define HD_ 48
#define HDP 64

// ---- output layout (flat floats in d_out) ----
#define OUT0_SIZE (B_*LQ*E_)
#define AW_OFF    (OUT0_SIZE)
#define AW_SIZE   (B_*LQ*LK)
#define NH_OFF    (AW_OFF + AW_SIZE)
#define SF_OFF    (NH_OFF + 4)
#define GV_OFF    (NH_OFF + 8)

// ---- workspace layout (bytes) ----
#define WOFF_PIN    0
#define WOFF_QFRAG  49152                                  // [bh][LQ/16][2][64][8] bf16 (zeroed pad)
#define WOFF_KFRAG  (WOFF_QFRAG + (size_t)B_*H_*LQ*HDP*2)  // [bh][LK/16][2][64][8] bf16 (zeroed pad)
#define WOFF_VFRAG  (WOFF_KFRAG + (size_t)B_*H_*LK*HDP*2)  // [bh][LK/64][3][2][64][8] bf16
#define WOFF_CTX    (WOFF_VFRAG + (size_t)B_*H_*HD_*LK*2)  // ctx frag-major [m/16][24][64][8]
#define WOFF_DINV   (WOFF_CTX + (size_t)B_*LQ*E_*2)
#define WOFF_H1     (WOFF_DINV + (size_t)B_*H_*LQ*4)
#define WOFF_H2     (WOFF_H1 + B_*E_*4)
#define WOFF_WBF    (WOFF_H2 + B_*(E_/2)*4)                // ipw frag bf16 [144][24][64][8]
#define WOFF_OWBF   (WOFF_WBF + (size_t)2304*768*2)        // outw frag bf16 [48][24][64][8]
#define WOFF_AO     (WOFF_OWBF + (size_t)768*768*2)        // f32 [B*LQ][E]  (aliases VBF)
#define WOFF_VBF    WOFF_AO                                // value frag bf16 (dead before AO written)
#define WS_SMALL    (WOFF_AO + (size_t)B_*LQ*E_*4)
#define WOFF_QBF    WS_SMALL                               // query frag bf16
#define WOFF_KBF    (WOFF_QBF + (size_t)B_*LQ*E_*2)        // key frag bf16
#define WS_FULL     (WOFF_KBF + (size_t)B_*LK*E_*2)
#define WS_ZERO_BYTES WOFF_VFRAG

typedef unsigned short u16;
typedef __attribute__((ext_vector_type(8))) short short8;
typedef __attribute__((ext_vector_type(4))) short short4v;
typedef __attribute__((ext_vector_type(4))) float floatx4;

#define SC2 0.20823506544914194f
#define MFMA16(a,b,c) __builtin_amdgcn_mfma_f32_16x16x32_bf16(a,b,c,0,0,0)

__device__ __forceinline__ u16 f2bf(float x) {
  union { float f; unsigned u; } v; v.f = x;
  unsigned r = v.u + 0x7fffu + ((v.u >> 16) & 1u);
  return (u16)(r >> 16);
}
// HW packed f32->bf16 (RNE): 1 instr replaces ~8 ops of manual rounding+pack.
__device__ __forceinline__ unsigned cvt_pk_bf16(float a, float b) {
  unsigned r;
  asm("v_cvt_pk_bf16_f32 %0, %1, %2" : "=v"(r) : "v"(a), "v"(b));
  return r;
}
__device__ __forceinline__ short8 ldfrag_f32(const float* p) {
  const float4* q4 = (const float4*)p;
  float4 a = q4[0], b = q4[1];
  short8 r;
  r[0]=(short)f2bf(a.x); r[1]=(short)f2bf(a.y); r[2]=(short)f2bf(a.z); r[3]=(short)f2bf(a.w);
  r[4]=(short)f2bf(b.x); r[5]=(short)f2bf(b.y); r[6]=(short)f2bf(b.z); r[7]=(short)f2bf(b.w);
  return r;
}
__device__ __forceinline__ short8 ldfrag_bf16(const u16* p) { return *(const short8*)p; }

__device__ __forceinline__ size_t qkfrag_idx(int bh, int ltiles, int tile,
                                             int half, int slot, int e) {
  return ((((size_t)bh*ltiles + tile)*2 + half)*64 + slot)*8 + e;
}

// ---- f32 [R][768] row-major -> bf16 fragment-major [R/16][24][64][8] -------
__global__ __launch_bounds__(256) void conv_frag_k(const float* __restrict__ src,
                                                   u16* __restrict__ dst) {
  __shared__ u16 ls[16][776];  // +8 pad: row stride 388 dw == 4 mod 32 banks
  int tid = threadIdx.x;
  size_t base = (size_t)blockIdx.x * 16 * 768;
  #pragma unroll
  for (int j=0;j<12;j++) {
    int i4 = tid + j*256;               // 3072 float4s
    int r = i4 / 192, c4 = i4 - r*192;
    float4 v = *(const float4*)(src + base + (size_t)r*768 + c4*4);
    ushort4 o;
    o.x = f2bf(v.x); o.y = f2bf(v.y); o.z = f2bf(v.z); o.w = f2bf(v.w);
    *(ushort4*)&ls[r][c4*4] = o;
  }
  __syncthreads();
  u16* db = dst + (size_t)blockIdx.x * 24 * 512;
  #pragma unroll
  for (int j=0;j<6;j++) {
    int cid = tid + j*256;              // 1536 chunks of 8
    int kt = cid >> 6, slot = cid & 63;
    int rr = slot & 15, qq = slot >> 4;
    *(short8*)(db + (size_t)(kt*64 + slot)*8) = *(const short8*)&ls[rr][kt*32 + qq*8];
  }
}

// ---- mask -> fragment pad slots ---------------------------------------------
// qfrag pad slot d=48 := 1.0 for every q row; kfrag pad slot d=48 := -1e30 for
// masked k rows. QK^T then accumulates -1e30 into masked scores via MFMA, so
// exp2 underflows to exactly 0 -- removes all per-score mask ops from both
// attention kernels. (d=48: half=1, quad=2, e=0; other pad slots stay zero.)
__global__ __launch_bounds__(256) void maskpad_k(const unsigned char* __restrict__ mask,
    u16* __restrict__ qfrag, u16* __restrict__ kfrag) {
  int tid = blockIdx.x*256 + threadIdx.x;            // 131072 threads
  if (tid < B_*H_*LQ) {
    int bh = tid >> 10, row = tid & (LQ-1);
    qfrag[qkfrag_idx(bh, LQ/16, row>>4, 1, 32 + (row&15), 0)] = 0x3F80; // bf16(1.0)
  }
  int bh = tid >> 11, row = tid & (LK-1);
  if (mask[(size_t)(bh>>4)*LK + row])
    kfrag[qkfrag_idx(bh, LK/16, row>>4, 1, 32 + (row&15), 0)] = f2bf(-1e30f);
}

// ---------------- pooling ----------------------------------------------------
__global__ __launch_bounds__(256) void pool_k(const float* __restrict__ query,
                                              const float* __restrict__ key,
                                              float* __restrict__ pin) {
  int bid = blockIdx.x;
  const float* src; int Lrows, fofs, b, fc, lch;
  if (bid < 96) { b = bid/24; int r = bid%24; fc = r/8;  lch = r%8;  src=query; Lrows=LQ; fofs=0; }
  else { int id = bid-96; b = id/48; int r = id%48; fc = r/16; lch = r%16; src=key; Lrows=LK; fofs=E_; }
  int f = fc*256 + threadIdx.x;
  const float* p = src + ((size_t)b*Lrows + lch*128)*E_ + f;
  float s = 0.f;
  #pragma unroll 4
  for (int i=0;i<128;i++) s += p[(size_t)i*E_];
  atomicAdd(&pin[b*2*E_ + fofs + f], s);
}

// ---------------- MLP head, fp32 ---------------------------------------------
__global__ __launch_bounds__(256) void mlp1_k(const float* __restrict__ pin,
    const float* __restrict__ Wp1, const float* __restrict__ bp1,
    float* __restrict__ h1) {
  __shared__ float sp[B_][2*E_];
  int tid = threadIdx.x;
  for (int j = tid; j < B_*2*E_; j += 256) {
    int b = j / (2*E_), c = j % (2*E_);
    sp[b][c] = pin[b*2*E_ + c] * (c < E_ ? (1.f/LQ) : (1.f/LK));
  }
  __syncthreads();
  int wv = tid >> 6, lane = tid & 63;
  int rbase = (blockIdx.x*4 + wv) * 4;
  for (int rr = 0; rr < 4; rr++) {
    int r = rbase + rr;
    const float* w = Wp1 + (size_t)r*(2*E_);
    float a0=0.f,a1=0.f,a2=0.f,a3=0.f;
    for (int i = lane; i < 2*E_; i += 64) {
      float wj = w[i];
      a0 += wj*sp[0][i]; a1 += wj*sp[1][i]; a2 += wj*sp[2][i]; a3 += wj*sp[3][i];
    }
    #pragma unroll
    for (int m=1;m<64;m<<=1){
      a0+=__shfl_xor(a0,m,64); a1+=__shfl_xor(a1,m,64);
      a2+=__shfl_xor(a2,m,64); a3+=__shfl_xor(a3,m,64);
    }
    if (lane == 0) {
      float bb = bp1[r];
      h1[0*E_+r]=fmaxf(a0+bb,0.f); h1[1*E_+r]=fmaxf(a1+bb,0.f);
      h1[2*E_+r]=fmaxf(a2+bb,0.f); h1[3*E_+r]=fmaxf(a3+bb,0.f);
    }
  }
}

__global__ __launch_bounds__(256) void mlp2_k(const float* __restrict__ h1,
    const float* __restrict__ Wp2, const float* __restrict__ bp2,
    float* __restrict__ h2) {
  __shared__ float sh[B_][E_];
  int tid = threadIdx.x;
  for (int j = tid; j < B_*E_; j += 256) sh[j/E_][j%E_] = h1[j];
  __syncthreads();
  int wv = tid >> 6, lane = tid & 63;
  int rbase = (blockIdx.x*4 + wv) * 4;
  for (int rr = 0; rr < 4; rr++) {
    int r = rbase + rr;
    const float* w = Wp2 + (size_t)r*E_;
    float a0=0.f,a1=0.f,a2=0.f,a3=0.f;
    for (int i = lane; i < E_; i += 64) {
      float wj = w[i];
      a0 += wj*sh[0][i]; a1 += wj*sh[1][i]; a2 += wj*sh[2][i]; a3 += wj*sh[3][i];
    }
    #pragma unroll
    for (int m=1;m<64;m<<=1){
      a0+=__shfl_xor(a0,m,64); a1+=__shfl_xor(a1,m,64);
      a2+=__shfl_xor(a2,m,64); a3+=__shfl_xor(a3,m,64);
    }
    if (lane == 0) {
      float bb = bp2[r];
      h2[0*(E_/2)+r]=fmaxf(a0+bb,0.f); h2[1*(E_/2)+r]=fmaxf(a1+bb,0.f);
      h2[2*(E_/2)+r]=fmaxf(a2+bb,0.f); h2[3*(E_/2)+r]=fmaxf(a3+bb,0.f);
    }
  }
}

__global__ __launch_bounds__(256) void mlp3_k(const float* __restrict__ h2,
    const float* __restrict__ Wp3, const float* __restrict__ bp3,
    float* __restrict__ out) {
  int tid = threadIdx.x, wv = tid >> 6, lane = tid & 63;
  float a0=0.f,a1=0.f,a2=0.f;
  for (int i = lane; i < E_/2; i += 64) {
    float x = h2[wv*(E_/2)+i];
    a0 += x*Wp3[i]; a1 += x*Wp3[(E_/2)+i]; a2 += x*Wp3[2*(E_/2)+i];
  }
  #pragma unroll
  for (int m=1;m<64;m<<=1){
    a0+=__shfl_xor(a0,m,64); a1+=__shfl_xor(a1,m,64); a2+=__shfl_xor(a2,m,64);
  }
  if (lane == 0) {
    float p0 = a0 + bp3[0], p1 = a1 + bp3[1], p2 = a2 + bp3[2];
    float s0 = 1.f/(1.f+expf(-p0));
    float s1 = 1.f/(1.f+expf(-p1));
    float s2 = 1.f/(1.f+expf(-p2));
    out[NH_OFF + wv] = rintf(s0*(H_-1) + 1.f);
    out[SF_OFF + wv] = s1*0.5f + 0.5f;
    out[GV_OFF + wv] = s2;
  }
}

// ---- 128m x 64n GEMM, frag-major bf16 operands, XCD-chunked dispatch --------
// C[m][n] = (sum_k A[m][k]*B[n][k] + bias[n]) * cscale
// cscale folds the 1/sqrt(HD)*log2(e) softmax scale into qfrag (1.0 elsewhere).
template<int MODE, bool ABF, int TSH>
__global__ __launch_bounds__(256) void gemm_fm(const void* __restrict__ Ap,
    const u16* __restrict__ Bf, const float* __restrict__ bias,
    void* __restrict__ Cp, float cscale) {
  int lane = threadIdx.x & 63, wv = threadIdx.x >> 6;
  int lc = lane & 15, quad = lane >> 4;
  int lid = blockIdx.y * gridDim.x + blockIdx.x;
  int xcd = lid & 7, rr = lid >> 3;
  int C = gridDim.y >> 3;
  int lx = rr % gridDim.x, ly = xcd*C + rr / gridDim.x;
  int wm = ly*128 + (wv & 1)*64;
  int wn = lx*64  + (wv >> 1)*32;
  int mt0 = wm >> 4, nt0 = wn >> 4;
  const float* Af = (const float*)Ap;
  const u16*  Abf = (const u16*)Ap;
  floatx4 acc[4][2];
  #pragma unroll
  for (int s=0;s<4;s++)
    #pragma unroll
    for (int t=0;t<2;t++) acc[s][t] = (floatx4){0.f,0.f,0.f,0.f};
  #pragma unroll 2
  for (int kt=0; kt<24; kt++) {
    short8 af[4], bf2[2];
    #pragma unroll
    for (int s=0;s<4;s++)
      af[s] = ABF ? ldfrag_bf16(Abf + ((size_t)(mt0+s)*24 + kt)*512 + lane*8)
                  : ldfrag_f32(Af + (size_t)(wm + s*16 + lc)*E_ + kt*32 + quad*8);
    #pragma unroll
    for (int t=0;t<2;t++)
      bf2[t] = ldfrag_bf16(Bf + ((size_t)(nt0+t)*24 + kt)*512 + lane*8);
    #pragma unroll
    for (int s=0;s<4;s++)
      #pragma unroll
      for (int t=0;t<2;t++)
        acc[s][t] = MFMA16(af[s], bf2[t], acc[s][t]);
  }
  #pragma unroll
  for (int s=0;s<4;s++)
    #pragma unroll
    for (int t=0;t<2;t++)
      #pragma unroll
      for (int r=0;r<4;r++) {
        int m = wm + s*16 + quad*4 + r;
        int n = wn + t*16 + lc;
        float v = (acc[s][t][r] + bias[n]) * cscale;
        if (MODE == 0) {
          ((float*)Cp)[(size_t)m*E_ + n] = v;
        } else if (MODE == 1) {
          int bi = m >> TSH, l = m & ((1<<TSH)-1);
          int hh = n / HD_, d = n - hh*HD_;
          int half = d >> 5, q2 = (d >> 3) & 3, e = d & 7;
          ((u16*)Cp)[qkfrag_idx(bi*H_+hh, (1<<TSH)>>4, l>>4, half, q2*16 + (l&15), e)]
            = f2bf(v);
        } else {
          int bi = m >> 11, kc = m & 2047;
          int hh = n / HD_, d = n - hh*HD_;
          int dt = d >> 4, nn = d & 15;
          int kt2 = kc >> 6, c0 = (kc >> 5) & 1, q2 = (kc >> 3) & 3, e = kc & 7;
          size_t idx = ((((size_t)(bi*H_+hh)*(LK/64) + kt2)*3 + dt)*2 + c0)*512
                       + (q2*16+nn)*8 + e;
          ((u16*)Cp)[idx] = f2bf(v);
        }
      }
}

// ---- fused attention: 8 waves, k-split in 2 halves, LDS combine -------------
// waves 0-3: k in [0,1024), waves 4-7: k in [1024,2048) for the same 128 q rows.
// Doubles waves/SIMD (2->4) at unchanged per-block K/V cache traffic.
// Mask + softmax scale pre-folded into fragments (see maskpad_k / gemm cscale).
__global__ __launch_bounds__(512) void attn_fused_k(const u16* __restrict__ qfrag,
    const u16* __restrict__ kfrag, const u16* __restrict__ vfrag,
    float* __restrict__ dinv, u16* __restrict__ ctxb) {
  __shared__ __align__(16) u16 lp[8][16][72];
  __shared__ float cacc[4][64][33];   // stride 33: bank = lane mod 32 -> 2-way (free)
  int lane = threadIdx.x & 63, wv = threadIdx.x >> 6;
  int wq = wv & 3, kw = wv >> 2;
  int lc = lane & 15, quad = lane >> 4;
  int b = blockIdx.z, h = blockIdx.y, bh = b*H_ + h;
  int qw0 = blockIdx.x*128 + wq*32;
  const u16* qb = qfrag + (size_t)bh*(LQ/16)*1024;
  const u16* kb = kfrag + (size_t)bh*(LK/16)*1024;
  const u16* vb = vfrag + (size_t)bh*(LK/64)*3072;
  short8 qf[2][2];
  #pragma unroll
  for (int qt=0;qt<2;qt++)
    #pragma unroll
    for (int hf=0;hf<2;hf++)
      qf[qt][hf] = ldfrag_bf16(qb + (((qw0>>4)+qt)*2 + hf)*512 + lane*8);
  floatx4 lv[2];
  lv[0] = (floatx4){0.f,0.f,0.f,0.f}; lv[1] = lv[0];
  floatx4 acc[2][3];
  #pragma unroll
  for (int qt=0;qt<2;qt++)
    #pragma unroll
    for (int dt=0;dt<3;dt++) acc[qt][dt] = (floatx4){0.f,0.f,0.f,0.f};

  int kend = (kw + 1) << 10;
  for (int k0 = kw << 10; k0 < kend; k0 += 64) {
    short8 kf[4][2];
    #pragma unroll
    for (int t=0;t<4;t++)
      #pragma unroll
      for (int hf=0;hf<2;hf++)
        kf[t][hf] = ldfrag_bf16(kb + (((k0>>4)+t)*2 + hf)*512 + lane*8);
    short8 vf[2][3];
    #pragma unroll
    for (int c0=0;c0<2;c0++)
      #pragma unroll
      for (int dt=0;dt<3;dt++)
        vf[c0][dt] = ldfrag_bf16(vb + (((k0>>6)*3 + dt)*2 + c0)*512 + lane*8);

    #pragma unroll
    for (int qt=0;qt<2;qt++) {
      #pragma unroll
      for (int t=0;t<4;t++) {
        floatx4 z = {0.f,0.f,0.f,0.f};
        floatx4 st = MFMA16(kf[t][0], qf[qt][0], MFMA16(kf[t][1], qf[qt][1], z));
        floatx4 p;
        #pragma unroll
        for (int r=0;r<4;r++) p[r] = __builtin_amdgcn_exp2f(st[r]);
        lv[qt] += p;                       // 4 independent accum chains
        uint2 pk2;
        pk2.x = cvt_pk_bf16(p[0], p[1]);
        pk2.y = cvt_pk_bf16(p[2], p[3]);
        *(uint2*)&lp[wv][lc][t*16 + quad*4] = pk2;
      }
      short8 pa0 = *(const short8*)&lp[wv][lc][quad*8];
      short8 pa1 = *(const short8*)&lp[wv][lc][32 + quad*8];
      #pragma unroll
      for (int dt=0;dt<3;dt++)
        acc[qt][dt] = MFMA16(pa1, vf[1][dt], MFMA16(pa0, vf[0][dt], acc[qt][dt]));
    }
  }
  float l0 = lv[0][0]+lv[0][1]+lv[0][2]+lv[0][3];
  float l1 = lv[1][0]+lv[1][1]+lv[1][2]+lv[1][3];
  if (kw) {                               // upper half: publish partials
    float* cb = &cacc[wq][lane][0];
    #pragma unroll
    for (int qt=0;qt<2;qt++)
      #pragma unroll
      for (int dt=0;dt<3;dt++)
        #pragma unroll
        for (int r=0;r<4;r++) cb[(qt*3+dt)*4 + r] = acc[qt][dt][r];
    cb[24] = l0; cb[25] = l1;
  }
  __syncthreads();
  if (kw) return;
  {                                       // lower half: combine
    const float* cb = &cacc[wq][lane][0];
    #pragma unroll
    for (int qt=0;qt<2;qt++)
      #pragma unroll
      for (int dt=0;dt<3;dt++)
        #pragma unroll
        for (int r=0;r<4;r++) acc[qt][dt][r] += cb[(qt*3+dt)*4 + r];
    l0 += cb[24]; l1 += cb[25];
  }
  float lq[2] = {l0, l1};
  #pragma unroll
  for (int qt=0;qt<2;qt++) {
    float s = lq[qt];
    s += __shfl_xor(s, 16, 64);
    s += __shfl_xor(s, 32, 64);
    float linv = 1.f/s;
    if (lane < 16) dinv[(size_t)bh*LQ + qw0 + qt*16 + lane] = linv;
    float li[4];
    #pragma unroll
    for (int r=0;r<4;r++) li[r] = __shfl(linv, quad*4 + r, 64);
    #pragma unroll
    for (int dt=0;dt<3;dt++)
      #pragma unroll
      for (int r=0;r<4;r++) {
        int mg = b*LQ + qw0 + qt*16 + quad*4 + r;
        int k  = h*HD_ + dt*16 + lc;
        size_t idx = (((size_t)(mg>>4)*(E_/32) + (k>>5))*64 + ((k>>3)&3)*16 + (mg&15))*8 + (k&7);
        ctxb[idx] = f2bf(acc[qt][dt][r]*li[r]);
      }
  }
}

// ---- attn_weights: 128q x 128k block tile, LDS-staged heads, dbuf -----------
// R1/R3 lesson: per-wave direct global frag reads for 16 heads = 537 MB L2/L3
// traffic at 2-3 waves/SIMD -> latency-bound at 52-65us. Now each 512-thread
// block stages the head's 128q- and 128k-slices (16KB+16KB) in LDS once,
// shared by 8 waves (2q x 4k, each 64q x 32k), double-buffered across heads:
// next head's global loads (regs) overlap current head's MFMA+exp2, ds_write
// lands after the barrier (T14). Traffic 537->268MB; 2 blocks/CU, 64KB LDS,
// ~100 VGPR -> 4 waves/SIMD. 1-D grid 512 with XCD decode: all 16 k-blocks of
// one (q-band, b) land on one XCD so its q-slice is L2-resident there.
#define AW_QSTR ((LQ/16)*1024)   // u16 elems per head in qfrag
#define AW_KSTR ((LK/16)*1024)   // u16 elems per head in kfrag

__global__ __launch_bounds__(512) void attn_weights_k(const u16* __restrict__ qfrag,
    const u16* __restrict__ kfrag, const float* __restrict__ dinv,
    float* __restrict__ aw) {
  __shared__ __align__(16) u16 sq[2][8192];   // [buf][tile(8)][half(2)][64][8]
  __shared__ __align__(16) u16 sk[2][8192];
  int tid = threadIdx.x;
  int lane = tid & 63, wv = tid >> 6;
  int lc = lane & 15, quad = lane >> 4;
  // decode 1-D block id: xcd = id&7 (HW round-robin) carries the q-band+batch
  // group; all 16 k-blocks of a group share one XCD's L2.
  int xcd = blockIdx.x & 7, rest = blockIdx.x >> 3;
  int kx = rest & 15, g3 = rest >> 4;          // kx: k-block 0..15, g3: 0..3
  int y = xcd, b = g3;                         // q-band 0..7, batch 0..3
  int qblk = y*128, kblk = kx*128;
  int wq = wv & 1, wk = wv >> 1;               // wave tile: 64q x 32k
  int qw0 = qblk + wq*64;
  int k0  = kblk + wk*32;
  const u16* qb0 = qfrag + (size_t)(b*H_)*AW_QSTR + (qblk>>4)*1024;
  const u16* kb0 = kfrag + (size_t)(b*H_)*AW_KSTR + (kblk>>4)*1024;
  const float* dv0 = dinv + (size_t)(b*H_)*LQ + qw0;
  floatx4 acc[4][2];
  #pragma unroll
  for (int qt=0;qt<4;qt++)
    #pragma unroll
    for (int t=0;t<2;t++) acc[qt][t] = (floatx4){0.f,0.f,0.f,0.f};

  short8 gq[2], gk[2];
  #pragma unroll
  for (int i=0;i<2;i++) {
    gq[i] = *(const short8*)(qb0 + (size_t)(tid + i*512)*8);
    gk[i] = *(const short8*)(kb0 + (size_t)(tid + i*512)*8);
  }
  #pragma unroll
  for (int i=0;i<2;i++) {
    *(short8*)&sq[0][(tid + i*512)*8] = gq[i];
    *(short8*)&sk[0][(tid + i*512)*8] = gk[i];
  }
  __syncthreads();

  for (int h=0; h<H_; h++) {
    int cur = h & 1;
    if (h+1 < H_) {                      // issue next head's loads early
      const u16* qbn = qb0 + (size_t)(h+1)*AW_QSTR;
      const u16* kbn = kb0 + (size_t)(h+1)*AW_KSTR;
      #pragma unroll
      for (int i=0;i<2;i++) {
        gq[i] = *(const short8*)(qbn + (size_t)(tid + i*512)*8);
        gk[i] = *(const short8*)(kbn + (size_t)(tid + i*512)*8);
      }
    }
    float di[4];
    const float* dvh = dv0 + (size_t)h*LQ;
    #pragma unroll
    for (int qt=0;qt<4;qt++) di[qt] = dvh[qt*16 + lc];
    short8 kf[2][2];
    #pragma unroll
    for (int t=0;t<2;t++)
      #pragma unroll
      for (int hf=0;hf<2;hf++)
        kf[t][hf] = *(const short8*)&sk[cur][(((wk*2+t)*2+hf)*64 + lane)*8];
    #pragma unroll
    for (int qt=0;qt<4;qt++) {
      short8 qf0 = *(const short8*)&sq[cur][(((wq*4+qt)*2+0)*64 + lane)*8];
      short8 qf1 = *(const short8*)&sq[cur][(((wq*4+qt)*2+1)*64 + lane)*8];
      #pragma unroll
      for (int t=0;t<2;t++) {
        floatx4 z = {0.f,0.f,0.f,0.f};
        floatx4 st = MFMA16(kf[t][0], qf0, MFMA16(kf[t][1], qf1, z));
        #pragma unroll
        for (int r=0;r<4;r++)
          acc[qt][t][r] += __builtin_amdgcn_exp2f(st[r]) * di[qt];
      }
    }
    __syncthreads();                     // all waves done reading buf cur
    if (h+1 < H_) {
      int nxt = cur ^ 1;
      #pragma unroll
      for (int i=0;i<2;i++) {
        *(short8*)&sq[nxt][(tid + i*512)*8] = gq[i];
        *(short8*)&sk[nxt][(tid + i*512)*8] = gk[i];
      }
    }
    __syncthreads();                     // writes visible for next head
  }
  const float inv16 = 1.f/16.f;
  #pragma unroll
  for (int qt=0;qt<4;qt++)
    #pragma unroll
    for (int t=0;t<2;t++) {
      floatx4 v = acc[qt][t];
      v[0]*=inv16; v[1]*=inv16; v[2]*=inv16; v[3]*=inv16;
      *(floatx4*)&aw[((size_t)b*LQ + qw0 + qt*16 + lc)*LK + k0 + t*16 + quad*4] = v;
    }
}

// ---------------- fused gate + residual + layernorm --------------------------
__global__ __launch_bounds__(256) void final_ln_k(const float* __restrict__ query,
    const float* __restrict__ ao, const float* __restrict__ lng,
    const float* __restrict__ lnb, float* __restrict__ out) {
  int row = blockIdx.x, b = row >> 10, tid = threadIdx.x;
  float sf = out[SF_OFF + b];
  float gv = out[GV_OFF + b];
  float c1 = 2.f - gv, c2 = sf*gv;
  const float* q = query + (size_t)row*E_;
  const float* a = ao + (size_t)row*E_;
  float x[3], s1 = 0.f, s2 = 0.f;
  #pragma unroll
  for (int i=0;i<3;i++){ int j = tid + i*256; float v = q[j]*c1 + a[j]*c2; x[i]=v; s1+=v; s2+=v*v; }
  #pragma unroll
  for (int m=1;m<64;m<<=1){ s1 += __shfl_xor(s1,m,64); s2 += __shfl_xor(s2,m,64); }
  __shared__ float r1[4], r2[4];
  int wv = tid >> 6;
  if ((tid & 63) == 0){ r1[wv]=s1; r2[wv]=s2; }
  __syncthreads();
  s1 = r1[0]+r1[1]+r1[2]+r1[3];
  s2 = r2[0]+r2[1]+r2[2]+r2[3];
  float mu = s1*(1.f/E_);
  float var = s2*(1.f/E_) - mu*mu;
  float rs = rsqrtf(var + 1e-5f);
  #pragma unroll
  for (int i=0;i<3;i++){ int j = tid + i*256; out[(size_t)row*E_ + j] = (x[i]-mu)*rs*lng[j] + lnb[j]; }
}

extern "C" void kernel_launch(void* const* d_in, const int* in_sizes, int n_in,
                              void* d_out, int out_size, void* d_ws, size_t ws_size,
                              hipStream_t stream) {
  const float* query = (const float*)d_in[0];
  const float* key   = (const float*)d_in[1];
  const float* value = (const float*)d_in[2];
  const unsigned char* mask = (const unsigned char*)d_in[3];
  const float* Wp1 = (const float*)d_in[4];
  const float* bp1 = (const float*)d_in[5];
  const float* Wp2 = (const float*)d_in[6];
  const float* bp2 = (const float*)d_in[7];
  const float* Wp3 = (const float*)d_in[8];
  const float* bp3 = (const float*)d_in[9];
  const float* ipw = (const float*)d_in[10];
  const float* ipb = (const float*)d_in[11];
  const float* outw = (const float*)d_in[12];
  const float* outb = (const float*)d_in[13];
  const float* lng = (const float*)d_in[14];
  const float* lnb = (const float*)d_in[15];
  float* out = (float*)d_out;
  char* ws = (char*)d_ws;
  if (ws_size < WS_SMALL) return;
  bool full = (ws_size >= WS_FULL);
  float* pin  = (float*)(ws + WOFF_PIN);
  u16* qfrag  = (u16*)(ws + WOFF_QFRAG);
  u16* kfrag  = (u16*)(ws + WOFF_KFRAG);
  u16* vfrag  = (u16*)(ws + WOFF_VFRAG);
  u16* ctxb   = (u16*)(ws + WOFF_CTX);
  float* dinv = (float*)(ws + WOFF_DINV);
  float* h1   = (float*)(ws + WOFF_H1);
  float* h2   = (float*)(ws + WOFF_H2);
  u16* wbf    = (u16*)(ws + WOFF_WBF);
  u16* owbf   = (u16*)(ws + WOFF_OWBF);
  float* ao   = (float*)(ws + WOFF_AO);
  u16* vbf    = (u16*)(ws + WOFF_VBF);   // aliases ao (dead before ao written)
  u16* qbf    = (u16*)(ws + WOFF_QBF);
  u16* kbf    = (u16*)(ws + WOFF_KBF);

  hipMemsetAsync(ws, 0, WS_ZERO_BYTES, stream);  // pin + q/k frag padding
  maskpad_k<<<512, 256, 0, stream>>>(mask, qfrag, kfrag);
  pool_k<<<288, 256, 0, stream>>>(query, key, pin);
  mlp1_k<<<48, 256, 0, stream>>>(pin, Wp1, bp1, h1);
  mlp2_k<<<24, 256, 0, stream>>>(h1, Wp2, bp2, h2);
  mlp3_k<<<1, 256, 0, stream>>>(h2, Wp3, bp3, out);

  conv_frag_k<<<144, 256, 0, stream>>>(ipw, wbf);
  conv_frag_k<<<48, 256, 0, stream>>>(outw, owbf);
  const u16* wq = wbf;
  const u16* wk = wbf + (size_t)48*24*512;
  const u16* wvv = wbf + (size_t)96*24*512;
  if (full) {
    conv_frag_k<<<256, 256, 0, stream>>>(query, qbf);
    conv_frag_k<<<512, 256, 0, stream>>>(key, kbf);
    conv_frag_k<<<512, 256, 0, stream>>>(value, vbf);
    gemm_fm<1,true,10><<<dim3(12,32), 256, 0, stream>>>((const void*)qbf, wq, ipb, (void*)qfrag, SC2);
    gemm_fm<1,true,11><<<dim3(12,64), 256, 0, stream>>>((const void*)kbf, wk, ipb + E_, (void*)kfrag, 1.f);
    gemm_fm<2,true,11><<<dim3(12,64), 256, 0, stream>>>((const void*)vbf, wvv, ipb + 2*E_, (void*)vfrag, 1.f);
  } else {
    gemm_fm<1,false,10><<<dim3(12,32), 256, 0, stream>>>((const void*)query, wq, ipb, (void*)qfrag, SC2);
    gemm_fm<1,false,11><<<dim3(12,64), 256, 0, stream>>>((const void*)key, wk, ipb + E_, (void*)kfrag, 1.f);
    gemm_fm<2,false,11><<<dim3(12,64), 256, 0, stream>>>((const void*)value, wvv, ipb + 2*E_, (void*)vfrag, 1.f);
  }
  attn_fused_k<<<dim3(8,16,4), 512, 0, stream>>>(qfrag, kfrag, vfrag, dinv, ctxb);
  attn_weights_k<<<512, 512, 0, stream>>>(qfrag, kfrag, dinv, out + AW_OFF);
  gemm_fm<0,true,10><<<dim3(12,32), 256, 0, stream>>>((const void*)ctxb, owbf, outb, (void*)ao, 1.f);
  final_ln_k<<<4096, 256, 0, stream>>>(query, ao, lng, lnb, out);
}

// Round 5
// 373.749 us; speedup vs baseline: 1.5519x; 1.0886x over previous
//
#include <hip/hip_runtime.h>

#define B_ 4
#define LQ 1024
#define LK 2048
#define E_ 768
#define H_ 16
#define HD_ 48
#define HDP 64

// ---- output layout (flat floats in d_out) ----
#define OUT0_SIZE (B_*LQ*E_)
#define AW_OFF    (OUT0_SIZE)
#define AW_SIZE   (B_*LQ*LK)
#define NH_OFF    (AW_OFF + AW_SIZE)
#define SF_OFF    (NH_OFF + 4)
#define GV_OFF    (NH_OFF + 8)

// ---- workspace layout (bytes) ----
#define WOFF_PIN    0
#define WOFF_QFRAG  49152                                  // [bh][LQ/16][2][64][8] bf16 (zeroed pad)
#define WOFF_KFRAG  (WOFF_QFRAG + (size_t)B_*H_*LQ*HDP*2)  // [bh][LK/16][2][64][8] bf16 (zeroed pad)
#define WOFF_VFRAG  (WOFF_KFRAG + (size_t)B_*H_*LK*HDP*2)  // [bh][LK/64][3][2][64][8] bf16
#define WOFF_CTX    (WOFF_VFRAG + (size_t)B_*H_*HD_*LK*2)  // ctx frag-major [m/16][24][64][8]
#define WOFF_DINV   (WOFF_CTX + (size_t)B_*LQ*E_*2)
#define WOFF_H1     (WOFF_DINV + (size_t)B_*H_*LQ*4)
#define WOFF_H2     (WOFF_H1 + B_*E_*4)
#define WOFF_WBF    (WOFF_H2 + B_*(E_/2)*4)                // ipw frag bf16 [144][24][64][8]
#define WOFF_OWBF   (WOFF_WBF + (size_t)2304*768*2)        // outw frag bf16 [48][24][64][8]
#define WOFF_AO     (WOFF_OWBF + (size_t)768*768*2)        // f32 [B*LQ][E]  (aliases VBF)
#define WOFF_VBF    WOFF_AO                                // value frag bf16 (dead before AO written)
#define WS_SMALL    (WOFF_AO + (size_t)B_*LQ*E_*4)
#define WOFF_QBF    WS_SMALL                               // query frag bf16
#define WOFF_KBF    (WOFF_QBF + (size_t)B_*LQ*E_*2)        // key frag bf16
#define WS_FULL     (WOFF_KBF + (size_t)B_*LK*E_*2)
#define WS_ZERO_BYTES WOFF_VFRAG

typedef unsigned short u16;
typedef __attribute__((ext_vector_type(8))) short short8;
typedef __attribute__((ext_vector_type(4))) short short4v;
typedef __attribute__((ext_vector_type(4))) float floatx4;

#define SC2 0.20823506544914194f
#define MFMA16(a,b,c) __builtin_amdgcn_mfma_f32_16x16x32_bf16(a,b,c,0,0,0)

__device__ __forceinline__ u16 f2bf(float x) {
  union { float f; unsigned u; } v; v.f = x;
  unsigned r = v.u + 0x7fffu + ((v.u >> 16) & 1u);
  return (u16)(r >> 16);
}
// HW packed f32->bf16 (RNE): 1 instr replaces ~8 ops of manual rounding+pack.
__device__ __forceinline__ unsigned cvt_pk_bf16(float a, float b) {
  unsigned r;
  asm("v_cvt_pk_bf16_f32 %0, %1, %2" : "=v"(r) : "v"(a), "v"(b));
  return r;
}
__device__ __forceinline__ short8 ldfrag_f32(const float* p) {
  const float4* q4 = (const float4*)p;
  float4 a = q4[0], b = q4[1];
  short8 r;
  r[0]=(short)f2bf(a.x); r[1]=(short)f2bf(a.y); r[2]=(short)f2bf(a.z); r[3]=(short)f2bf(a.w);
  r[4]=(short)f2bf(b.x); r[5]=(short)f2bf(b.y); r[6]=(short)f2bf(b.z); r[7]=(short)f2bf(b.w);
  return r;
}
__device__ __forceinline__ short8 ldfrag_bf16(const u16* p) { return *(const short8*)p; }

__device__ __forceinline__ size_t qkfrag_idx(int bh, int ltiles, int tile,
                                             int half, int slot, int e) {
  return ((((size_t)bh*ltiles + tile)*2 + half)*64 + slot)*8 + e;
}

// ---- f32 [R][768] row-major -> bf16 fragment-major [R/16][24][64][8] -------
__global__ __launch_bounds__(256) void conv_frag_k(const float* __restrict__ src,
                                                   u16* __restrict__ dst) {
  __shared__ u16 ls[16][776];  // +8 pad: row stride 388 dw == 4 mod 32 banks
  int tid = threadIdx.x;
  size_t base = (size_t)blockIdx.x * 16 * 768;
  #pragma unroll
  for (int j=0;j<12;j++) {
    int i4 = tid + j*256;               // 3072 float4s
    int r = i4 / 192, c4 = i4 - r*192;
    float4 v = *(const float4*)(src + base + (size_t)r*768 + c4*4);
    ushort4 o;
    o.x = f2bf(v.x); o.y = f2bf(v.y); o.z = f2bf(v.z); o.w = f2bf(v.w);
    *(ushort4*)&ls[r][c4*4] = o;
  }
  __syncthreads();
  u16* db = dst + (size_t)blockIdx.x * 24 * 512;
  #pragma unroll
  for (int j=0;j<6;j++) {
    int cid = tid + j*256;              // 1536 chunks of 8
    int kt = cid >> 6, slot = cid & 63;
    int rr = slot & 15, qq = slot >> 4;
    *(short8*)(db + (size_t)(kt*64 + slot)*8) = *(const short8*)&ls[rr][kt*32 + qq*8];
  }
}

// ---- mask -> fragment pad slots ---------------------------------------------
// qfrag pad slot d=48 := 1.0 for every q row; kfrag pad slot d=48 := -1e30 for
// masked k rows. QK^T then accumulates -1e30 into masked scores via MFMA, so
// exp2 underflows to exactly 0 -- removes all per-score mask ops from both
// attention kernels. (d=48: half=1, quad=2, e=0; other pad slots stay zero.)
__global__ __launch_bounds__(256) void maskpad_k(const unsigned char* __restrict__ mask,
    u16* __restrict__ qfrag, u16* __restrict__ kfrag) {
  int tid = blockIdx.x*256 + threadIdx.x;            // 131072 threads
  if (tid < B_*H_*LQ) {
    int bh = tid >> 10, row = tid & (LQ-1);
    qfrag[qkfrag_idx(bh, LQ/16, row>>4, 1, 32 + (row&15), 0)] = 0x3F80; // bf16(1.0)
  }
  int bh = tid >> 11, row = tid & (LK-1);
  if (mask[(size_t)(bh>>4)*LK + row])
    kfrag[qkfrag_idx(bh, LK/16, row>>4, 1, 32 + (row&15), 0)] = f2bf(-1e30f);
}

// ---------------- pooling: fully-unrolled 128-row reduce, 4 partial sums -----
__global__ __launch_bounds__(256) void pool_k(const float* __restrict__ query,
                                              const float* __restrict__ key,
                                              float* __restrict__ pin) {
  int bid = blockIdx.x;
  const float* src; int Lrows, fofs, b, fc, lch;
  if (bid < 96) { b = bid/24; int r = bid%24; fc = r/8;  lch = r%8;  src=query; Lrows=LQ; fofs=0; }
  else { int id = bid-96; b = id/48; int r = id%48; fc = r/16; lch = r%16; src=key; Lrows=LK; fofs=E_; }
  int f = fc*256 + threadIdx.x;
  const float* p = src + ((size_t)b*Lrows + lch*128)*E_ + f;
  float s0=0.f, s1=0.f, s2=0.f, s3=0.f;
  #pragma unroll
  for (int i=0;i<128;i+=4) {
    s0 += p[(size_t)(i+0)*E_];
    s1 += p[(size_t)(i+1)*E_];
    s2 += p[(size_t)(i+2)*E_];
    s3 += p[(size_t)(i+3)*E_];
  }
  atomicAdd(&pin[b*2*E_ + fofs + f], (s0+s1)+(s2+s3));
}

// ---------------- MLP head, fp32 ---------------------------------------------
// R4 lesson: dynamic-bound scalar dot loops serialize at memory latency
// (mlp1 was 49.9us at 0.55% VALUBusy). Now: one wave per output row, weight
// row loaded as fully-unrolled float4 chunks (all loads in flight before one
// wait), LDS float4 dot, shuffle reduce.
__global__ __launch_bounds__(256) void mlp1_k(const float* __restrict__ pin,
    const float* __restrict__ Wp1, const float* __restrict__ bp1,
    float* __restrict__ h1) {
  __shared__ float sp[B_][2*E_];
  int tid = threadIdx.x;
  for (int j = tid; j < B_*2*E_; j += 256) {
    int c = j % (2*E_);
    sp[j/(2*E_)][c] = pin[j] * (c < E_ ? (1.f/LQ) : (1.f/LK));
  }
  __syncthreads();
  int wv = tid >> 6, lane = tid & 63;
  int r = blockIdx.x*4 + wv;                       // grid 192 -> rows 0..767
  const float4* w4 = (const float4*)(Wp1 + (size_t)r*(2*E_));
  float4 wreg[6];
  #pragma unroll
  for (int u=0;u<6;u++) wreg[u] = w4[lane + u*64]; // 384 float4 per row
  float a[B_] = {0.f,0.f,0.f,0.f};
  #pragma unroll
  for (int u=0;u<6;u++)
    #pragma unroll
    for (int b=0;b<B_;b++) {
      float4 s4 = *(const float4*)&sp[b][(lane + u*64)*4];
      a[b] += wreg[u].x*s4.x + wreg[u].y*s4.y + wreg[u].z*s4.z + wreg[u].w*s4.w;
    }
  #pragma unroll
  for (int m=1;m<64;m<<=1)
    #pragma unroll
    for (int b=0;b<B_;b++) a[b] += __shfl_xor(a[b], m, 64);
  if (lane == 0) {
    float bb = bp1[r];
    #pragma unroll
    for (int b=0;b<B_;b++) h1[b*E_ + r] = fmaxf(a[b]+bb, 0.f);
  }
}

__global__ __launch_bounds__(256) void mlp2_k(const float* __restrict__ h1,
    const float* __restrict__ Wp2, const float* __restrict__ bp2,
    float* __restrict__ h2) {
  __shared__ float sh[B_][E_];
  int tid = threadIdx.x;
  for (int j = tid; j < B_*E_; j += 256) sh[j/E_][j%E_] = h1[j];
  __syncthreads();
  int wv = tid >> 6, lane = tid & 63;
  int r = blockIdx.x*4 + wv;                       // grid 96 -> rows 0..383
  const float4* w4 = (const float4*)(Wp2 + (size_t)r*E_);
  float4 wreg[3];
  #pragma unroll
  for (int u=0;u<3;u++) wreg[u] = w4[lane + u*64]; // 192 float4 per row
  float a[B_] = {0.f,0.f,0.f,0.f};
  #pragma unroll
  for (int u=0;u<3;u++)
    #pragma unroll
    for (int b=0;b<B_;b++) {
      float4 s4 = *(const float4*)&sh[b][(lane + u*64)*4];
      a[b] += wreg[u].x*s4.x + wreg[u].y*s4.y + wreg[u].z*s4.z + wreg[u].w*s4.w;
    }
  #pragma unroll
  for (int m=1;m<64;m<<=1)
    #pragma unroll
    for (int b=0;b<B_;b++) a[b] += __shfl_xor(a[b], m, 64);
  if (lane == 0) {
    float bb = bp2[r];
    #pragma unroll
    for (int b=0;b<B_;b++) h2[b*(E_/2) + r] = fmaxf(a[b]+bb, 0.f);
  }
}

__global__ __launch_bounds__(256) void mlp3_k(const float* __restrict__ h2,
    const float* __restrict__ Wp3, const float* __restrict__ bp3,
    float* __restrict__ out) {
  int tid = threadIdx.x, wv = tid >> 6, lane = tid & 63;
  float a0=0.f,a1=0.f,a2=0.f;
  #pragma unroll
  for (int u=0;u<6;u++) {
    int i = lane + u*64;
    float x = h2[wv*(E_/2)+i];
    a0 += x*Wp3[i]; a1 += x*Wp3[(E_/2)+i]; a2 += x*Wp3[2*(E_/2)+i];
  }
  #pragma unroll
  for (int m=1;m<64;m<<=1){
    a0+=__shfl_xor(a0,m,64); a1+=__shfl_xor(a1,m,64); a2+=__shfl_xor(a2,m,64);
  }
  if (lane == 0) {
    float p0 = a0 + bp3[0], p1 = a1 + bp3[1], p2 = a2 + bp3[2];
    float s0 = 1.f/(1.f+expf(-p0));
    float s1 = 1.f/(1.f+expf(-p1));
    float s2 = 1.f/(1.f+expf(-p2));
    out[NH_OFF + wv] = rintf(s0*(H_-1) + 1.f);
    out[SF_OFF + wv] = s1*0.5f + 0.5f;
    out[GV_OFF + wv] = s2;
  }
}

// ---- 128m x 64n GEMM, frag-major bf16 operands, XCD-chunked dispatch --------
// C[m][n] = (sum_k A[m][k]*B[n][k] + bias[n]) * cscale
// cscale folds the 1/sqrt(HD)*log2(e) softmax scale into qfrag (1.0 elsewhere).
template<int MODE, bool ABF, int TSH>
__global__ __launch_bounds__(256) void gemm_fm(const void* __restrict__ Ap,
    const u16* __restrict__ Bf, const float* __restrict__ bias,
    void* __restrict__ Cp, float cscale) {
  int lane = threadIdx.x & 63, wv = threadIdx.x >> 6;
  int lc = lane & 15, quad = lane >> 4;
  int lid = blockIdx.y * gridDim.x + blockIdx.x;
  int xcd = lid & 7, rr = lid >> 3;
  int C = gridDim.y >> 3;
  int lx = rr % gridDim.x, ly = xcd*C + rr / gridDim.x;
  int wm = ly*128 + (wv & 1)*64;
  int wn = lx*64  + (wv >> 1)*32;
  int mt0 = wm >> 4, nt0 = wn >> 4;
  const float* Af = (const float*)Ap;
  const u16*  Abf = (const u16*)Ap;
  floatx4 acc[4][2];
  #pragma unroll
  for (int s=0;s<4;s++)
    #pragma unroll
    for (int t=0;t<2;t++) acc[s][t] = (floatx4){0.f,0.f,0.f,0.f};
  #pragma unroll 2
  for (int kt=0; kt<24; kt++) {
    short8 af[4], bf2[2];
    #pragma unroll
    for (int s=0;s<4;s++)
      af[s] = ABF ? ldfrag_bf16(Abf + ((size_t)(mt0+s)*24 + kt)*512 + lane*8)
                  : ldfrag_f32(Af + (size_t)(wm + s*16 + lc)*E_ + kt*32 + quad*8);
    #pragma unroll
    for (int t=0;t<2;t++)
      bf2[t] = ldfrag_bf16(Bf + ((size_t)(nt0+t)*24 + kt)*512 + lane*8);
    #pragma unroll
    for (int s=0;s<4;s++)
      #pragma unroll
      for (int t=0;t<2;t++)
        acc[s][t] = MFMA16(af[s], bf2[t], acc[s][t]);
  }
  #pragma unroll
  for (int s=0;s<4;s++)
    #pragma unroll
    for (int t=0;t<2;t++)
      #pragma unroll
      for (int r=0;r<4;r++) {
        int m = wm + s*16 + quad*4 + r;
        int n = wn + t*16 + lc;
        float v = (acc[s][t][r] + bias[n]) * cscale;
        if (MODE == 0) {
          ((float*)Cp)[(size_t)m*E_ + n] = v;
        } else if (MODE == 1) {
          int bi = m >> TSH, l = m & ((1<<TSH)-1);
          int hh = n / HD_, d = n - hh*HD_;
          int half = d >> 5, q2 = (d >> 3) & 3, e = d & 7;
          ((u16*)Cp)[qkfrag_idx(bi*H_+hh, (1<<TSH)>>4, l>>4, half, q2*16 + (l&15), e)]
            = f2bf(v);
        } else {
          int bi = m >> 11, kc = m & 2047;
          int hh = n / HD_, d = n - hh*HD_;
          int dt = d >> 4, nn = d & 15;
          int kt2 = kc >> 6, c0 = (kc >> 5) & 1, q2 = (kc >> 3) & 3, e = kc & 7;
          size_t idx = ((((size_t)(bi*H_+hh)*(LK/64) + kt2)*3 + dt)*2 + c0)*512
                       + (q2*16+nn)*8 + e;
          ((u16*)Cp)[idx] = f2bf(v);
        }
      }
}

// ---- fused attention: 8 waves, k-split in 2 halves, LDS combine -------------
// waves 0-3: k in [0,1024), waves 4-7: k in [1024,2048) for the same 128 q rows.
// Doubles waves/SIMD (2->4) at unchanged per-block K/V cache traffic.
// Mask + softmax scale pre-folded into fragments (see maskpad_k / gemm cscale).
__global__ __launch_bounds__(512) void attn_fused_k(const u16* __restrict__ qfrag,
    const u16* __restrict__ kfrag, const u16* __restrict__ vfrag,
    float* __restrict__ dinv, u16* __restrict__ ctxb) {
  __shared__ __align__(16) u16 lp[8][16][72];
  __shared__ float cacc[4][64][33];   // stride 33: bank = lane mod 32 -> 2-way (free)
  int lane = threadIdx.x & 63, wv = threadIdx.x >> 6;
  int wq = wv & 3, kw = wv >> 2;
  int lc = lane & 15, quad = lane >> 4;
  int b = blockIdx.z, h = blockIdx.y, bh = b*H_ + h;
  int qw0 = blockIdx.x*128 + wq*32;
  const u16* qb = qfrag + (size_t)bh*(LQ/16)*1024;
  const u16* kb = kfrag + (size_t)bh*(LK/16)*1024;
  const u16* vb = vfrag + (size_t)bh*(LK/64)*3072;
  short8 qf[2][2];
  #pragma unroll
  for (int qt=0;qt<2;qt++)
    #pragma unroll
    for (int hf=0;hf<2;hf++)
      qf[qt][hf] = ldfrag_bf16(qb + (((qw0>>4)+qt)*2 + hf)*512 + lane*8);
  floatx4 lv[2];
  lv[0] = (floatx4){0.f,0.f,0.f,0.f}; lv[1] = lv[0];
  floatx4 acc[2][3];
  #pragma unroll
  for (int qt=0;qt<2;qt++)
    #pragma unroll
    for (int dt=0;dt<3;dt++) acc[qt][dt] = (floatx4){0.f,0.f,0.f,0.f};

  int kend = (kw + 1) << 10;
  for (int k0 = kw << 10; k0 < kend; k0 += 64) {
    short8 kf[4][2];
    #pragma unroll
    for (int t=0;t<4;t++)
      #pragma unroll
      for (int hf=0;hf<2;hf++)
        kf[t][hf] = ldfrag_bf16(kb + (((k0>>4)+t)*2 + hf)*512 + lane*8);
    short8 vf[2][3];
    #pragma unroll
    for (int c0=0;c0<2;c0++)
      #pragma unroll
      for (int dt=0;dt<3;dt++)
        vf[c0][dt] = ldfrag_bf16(vb + (((k0>>6)*3 + dt)*2 + c0)*512 + lane*8);

    #pragma unroll
    for (int qt=0;qt<2;qt++) {
      #pragma unroll
      for (int t=0;t<4;t++) {
        floatx4 z = {0.f,0.f,0.f,0.f};
        floatx4 st = MFMA16(kf[t][0], qf[qt][0], MFMA16(kf[t][1], qf[qt][1], z));
        floatx4 p;
        #pragma unroll
        for (int r=0;r<4;r++) p[r] = __builtin_amdgcn_exp2f(st[r]);
        lv[qt] += p;                       // 4 independent accum chains
        uint2 pk2;
        pk2.x = cvt_pk_bf16(p[0], p[1]);
        pk2.y = cvt_pk_bf16(p[2], p[3]);
        *(uint2*)&lp[wv][lc][t*16 + quad*4] = pk2;
      }
      short8 pa0 = *(const short8*)&lp[wv][lc][quad*8];
      short8 pa1 = *(const short8*)&lp[wv][lc][32 + quad*8];
      #pragma unroll
      for (int dt=0;dt<3;dt++)
        acc[qt][dt] = MFMA16(pa1, vf[1][dt], MFMA16(pa0, vf[0][dt], acc[qt][dt]));
    }
  }
  float l0 = lv[0][0]+lv[0][1]+lv[0][2]+lv[0][3];
  float l1 = lv[1][0]+lv[1][1]+lv[1][2]+lv[1][3];
  if (kw) {                               // upper half: publish partials
    float* cb = &cacc[wq][lane][0];
    #pragma unroll
    for (int qt=0;qt<2;qt++)
      #pragma unroll
      for (int dt=0;dt<3;dt++)
        #pragma unroll
        for (int r=0;r<4;r++) cb[(qt*3+dt)*4 + r] = acc[qt][dt][r];
    cb[24] = l0; cb[25] = l1;
  }
  __syncthreads();
  if (kw) return;
  {                                       // lower half: combine
    const float* cb = &cacc[wq][lane][0];
    #pragma unroll
    for (int qt=0;qt<2;qt++)
      #pragma unroll
      for (int dt=0;dt<3;dt++)
        #pragma unroll
        for (int r=0;r<4;r++) acc[qt][dt][r] += cb[(qt*3+dt)*4 + r];
    l0 += cb[24]; l1 += cb[25];
  }
  float lq[2] = {l0, l1};
  #pragma unroll
  for (int qt=0;qt<2;qt++) {
    float s = lq[qt];
    s += __shfl_xor(s, 16, 64);
    s += __shfl_xor(s, 32, 64);
    float linv = 1.f/s;
    if (lane < 16) dinv[(size_t)bh*LQ + qw0 + qt*16 + lane] = linv;
    float li[4];
    #pragma unroll
    for (int r=0;r<4;r++) li[r] = __shfl(linv, quad*4 + r, 64);
    #pragma unroll
    for (int dt=0;dt<3;dt++)
      #pragma unroll
      for (int r=0;r<4;r++) {
        int mg = b*LQ + qw0 + qt*16 + quad*4 + r;
        int k  = h*HD_ + dt*16 + lc;
        size_t idx = (((size_t)(mg>>4)*(E_/32) + (k>>5))*64 + ((k>>3)&3)*16 + (mg&15))*8 + (k&7);
        ctxb[idx] = f2bf(acc[qt][dt][r]*li[r]);
      }
  }
}

// ---- attn_weights: 128q x 128k block tile, LDS-staged heads, dbuf -----------
#define AW_QSTR ((LQ/16)*1024)   // u16 elems per head in qfrag
#define AW_KSTR ((LK/16)*1024)   // u16 elems per head in kfrag

__global__ __launch_bounds__(512) void attn_weights_k(const u16* __restrict__ qfrag,
    const u16* __restrict__ kfrag, const float* __restrict__ dinv,
    float* __restrict__ aw) {
  __shared__ __align__(16) u16 sq[2][8192];   // [buf][tile(8)][half(2)][64][8]
  __shared__ __align__(16) u16 sk[2][8192];
  int tid = threadIdx.x;
  int lane = tid & 63, wv = tid >> 6;
  int lc = lane & 15, quad = lane >> 4;
  int xcd = blockIdx.x & 7, rest = blockIdx.x >> 3;
  int kx = rest & 15, g3 = rest >> 4;          // kx: k-block 0..15, g3: 0..3
  int y = xcd, b = g3;                         // q-band 0..7, batch 0..3
  int qblk = y*128, kblk = kx*128;
  int wq = wv & 1, wk = wv >> 1;               // wave tile: 64q x 32k
  int qw0 = qblk + wq*64;
  int k0  = kblk + wk*32;
  const u16* qb0 = qfrag + (size_t)(b*H_)*AW_QSTR + (qblk>>4)*1024;
  const u16* kb0 = kfrag + (size_t)(b*H_)*AW_KSTR + (kblk>>4)*1024;
  const float* dv0 = dinv + (size_t)(b*H_)*LQ + qw0;
  floatx4 acc[4][2];
  #pragma unroll
  for (int qt=0;qt<4;qt++)
    #pragma unroll
    for (int t=0;t<2;t++) acc[qt][t] = (floatx4){0.f,0.f,0.f,0.f};

  short8 gq[2], gk[2];
  #pragma unroll
  for (int i=0;i<2;i++) {
    gq[i] = *(const short8*)(qb0 + (size_t)(tid + i*512)*8);
    gk[i] = *(const short8*)(kb0 + (size_t)(tid + i*512)*8);
  }
  #pragma unroll
  for (int i=0;i<2;i++) {
    *(short8*)&sq[0][(tid + i*512)*8] = gq[i];
    *(short8*)&sk[0][(tid + i*512)*8] = gk[i];
  }
  __syncthreads();

  for (int h=0; h<H_; h++) {
    int cur = h & 1;
    if (h+1 < H_) {                      // issue next head's loads early
      const u16* qbn = qb0 + (size_t)(h+1)*AW_QSTR;
      const u16* kbn = kb0 + (size_t)(h+1)*AW_KSTR;
      #pragma unroll
      for (int i=0;i<2;i++) {
        gq[i] = *(const short8*)(qbn + (size_t)(tid + i*512)*8);
        gk[i] = *(const short8*)(kbn + (size_t)(tid + i*512)*8);
      }
    }
    float di[4];
    const float* dvh = dv0 + (size_t)h*LQ;
    #pragma unroll
    for (int qt=0;qt<4;qt++) di[qt] = dvh[qt*16 + lc];
    short8 kf[2][2];
    #pragma unroll
    for (int t=0;t<2;t++)
      #pragma unroll
      for (int hf=0;hf<2;hf++)
        kf[t][hf] = *(const short8*)&sk[cur][(((wk*2+t)*2+hf)*64 + lane)*8];
    #pragma unroll
    for (int qt=0;qt<4;qt++) {
      short8 qf0 = *(const short8*)&sq[cur][(((wq*4+qt)*2+0)*64 + lane)*8];
      short8 qf1 = *(const short8*)&sq[cur][(((wq*4+qt)*2+1)*64 + lane)*8];
      #pragma unroll
      for (int t=0;t<2;t++) {
        floatx4 z = {0.f,0.f,0.f,0.f};
        floatx4 st = MFMA16(kf[t][0], qf0, MFMA16(kf[t][1], qf1, z));
        #pragma unroll
        for (int r=0;r<4;r++)
          acc[qt][t][r] += __builtin_amdgcn_exp2f(st[r]) * di[qt];
      }
    }
    __syncthreads();                     // all waves done reading buf cur
    if (h+1 < H_) {
      int nxt = cur ^ 1;
      #pragma unroll
      for (int i=0;i<2;i++) {
        *(short8*)&sq[nxt][(tid + i*512)*8] = gq[i];
        *(short8*)&sk[nxt][(tid + i*512)*8] = gk[i];
      }
    }
    __syncthreads();                     // writes visible for next head
  }
  const float inv16 = 1.f/16.f;
  #pragma unroll
  for (int qt=0;qt<4;qt++)
    #pragma unroll
    for (int t=0;t<2;t++) {
      floatx4 v = acc[qt][t];
      v[0]*=inv16; v[1]*=inv16; v[2]*=inv16; v[3]*=inv16;
      *(floatx4*)&aw[((size_t)b*LQ + qw0 + qt*16 + lc)*LK + k0 + t*16 + quad*4] = v;
    }
}

// ---------------- fused gate + residual + layernorm --------------------------
__global__ __launch_bounds__(256) void final_ln_k(const float* __restrict__ query,
    const float* __restrict__ ao, const float* __restrict__ lng,
    const float* __restrict__ lnb, float* __restrict__ out) {
  int row = blockIdx.x, b = row >> 10, tid = threadIdx.x;
  float sf = out[SF_OFF + b];
  float gv = out[GV_OFF + b];
  float c1 = 2.f - gv, c2 = sf*gv;
  const float* q = query + (size_t)row*E_;
  const float* a = ao + (size_t)row*E_;
  float x[3], s1 = 0.f, s2 = 0.f;
  #pragma unroll
  for (int i=0;i<3;i++){ int j = tid + i*256; float v = q[j]*c1 + a[j]*c2; x[i]=v; s1+=v; s2+=v*v; }
  #pragma unroll
  for (int m=1;m<64;m<<=1){ s1 += __shfl_xor(s1,m,64); s2 += __shfl_xor(s2,m,64); }
  __shared__ float r1[4], r2[4];
  int wv = tid >> 6;
  if ((tid & 63) == 0){ r1[wv]=s1; r2[wv]=s2; }
  __syncthreads();
  s1 = r1[0]+r1[1]+r1[2]+r1[3];
  s2 = r2[0]+r2[1]+r2[2]+r2[3];
  float mu = s1*(1.f/E_);
  float var = s2*(1.f/E_) - mu*mu;
  float rs = rsqrtf(var + 1e-5f);
  #pragma unroll
  for (int i=0;i<3;i++){ int j = tid + i*256; out[(size_t)row*E_ + j] = (x[i]-mu)*rs*lng[j] + lnb[j]; }
}

extern "C" void kernel_launch(void* const* d_in, const int* in_sizes, int n_in,
                              void* d_out, int out_size, void* d_ws, size_t ws_size,
                              hipStream_t stream) {
  const float* query = (const float*)d_in[0];
  const float* key   = (const float*)d_in[1];
  const float* value = (const float*)d_in[2];
  const unsigned char* mask = (const unsigned char*)d_in[3];
  const float* Wp1 = (const float*)d_in[4];
  const float* bp1 = (const float*)d_in[5];
  const float* Wp2 = (const float*)d_in[6];
  const float* bp2 = (const float*)d_in[7];
  const float* Wp3 = (const float*)d_in[8];
  const float* bp3 = (const float*)d_in[9];
  const float* ipw = (const float*)d_in[10];
  const float* ipb = (const float*)d_in[11];
  const float* outw = (const float*)d_in[12];
  const float* outb = (const float*)d_in[13];
  const float* lng = (const float*)d_in[14];
  const float* lnb = (const float*)d_in[15];
  float* out = (float*)d_out;
  char* ws = (char*)d_ws;
  if (ws_size < WS_SMALL) return;
  bool full = (ws_size >= WS_FULL);
  float* pin  = (float*)(ws + WOFF_PIN);
  u16* qfrag  = (u16*)(ws + WOFF_QFRAG);
  u16* kfrag  = (u16*)(ws + WOFF_KFRAG);
  u16* vfrag  = (u16*)(ws + WOFF_VFRAG);
  u16* ctxb   = (u16*)(ws + WOFF_CTX);
  float* dinv = (float*)(ws + WOFF_DINV);
  float* h1   = (float*)(ws + WOFF_H1);
  float* h2   = (float*)(ws + WOFF_H2);
  u16* wbf    = (u16*)(ws + WOFF_WBF);
  u16* owbf   = (u16*)(ws + WOFF_OWBF);
  float* ao   = (float*)(ws + WOFF_AO);
  u16* vbf    = (u16*)(ws + WOFF_VBF);   // aliases ao (dead before ao written)
  u16* qbf    = (u16*)(ws + WOFF_QBF);
  u16* kbf    = (u16*)(ws + WOFF_KBF);

  hipMemsetAsync(ws, 0, WS_ZERO_BYTES, stream);  // pin + q/k frag padding
  maskpad_k<<<512, 256, 0, stream>>>(mask, qfrag, kfrag);
  pool_k<<<288, 256, 0, stream>>>(query, key, pin);
  mlp1_k<<<192, 256, 0, stream>>>(pin, Wp1, bp1, h1);
  mlp2_k<<<96, 256, 0, stream>>>(h1, Wp2, bp2, h2);
  mlp3_k<<<1, 256, 0, stream>>>(h2, Wp3, bp3, out);

  conv_frag_k<<<144, 256, 0, stream>>>(ipw, wbf);
  conv_frag_k<<<48, 256, 0, stream>>>(outw, owbf);
  const u16* wq = wbf;
  const u16* wk = wbf + (size_t)48*24*512;
  const u16* wvv = wbf + (size_t)96*24*512;
  if (full) {
    conv_frag_k<<<256, 256, 0, stream>>>(query, qbf);
    conv_frag_k<<<512, 256, 0, stream>>>(key, kbf);
    conv_frag_k<<<512, 256, 0, stream>>>(value, vbf);
    gemm_fm<1,true,10><<<dim3(12,32), 256, 0, stream>>>((const void*)qbf, wq, ipb, (void*)qfrag, SC2);
    gemm_fm<1,true,11><<<dim3(12,64), 256, 0, stream>>>((const void*)kbf, wk, ipb + E_, (void*)kfrag, 1.f);
    gemm_fm<2,true,11><<<dim3(12,64), 256, 0, stream>>>((const void*)vbf, wvv, ipb + 2*E_, (void*)vfrag, 1.f);
  } else {
    gemm_fm<1,false,10><<<dim3(12,32), 256, 0, stream>>>((const void*)query, wq, ipb, (void*)qfrag, SC2);
    gemm_fm<1,false,11><<<dim3(12,64), 256, 0, stream>>>((const void*)key, wk, ipb + E_, (void*)kfrag, 1.f);
    gemm_fm<2,false,11><<<dim3(12,64), 256, 0, stream>>>((const void*)value, wvv, ipb + 2*E_, (void*)vfrag, 1.f);
  }
  attn_fused_k<<<dim3(8,16,4), 512, 0, stream>>>(qfrag, kfrag, vfrag, dinv, ctxb);
  attn_weights_k<<<512, 512, 0, stream>>>(qfrag, kfrag, dinv, out + AW_OFF);
  gemm_fm<0,true,10><<<dim3(12,32), 256, 0, stream>>>((const void*)ctxb, owbf, outb, (void*)ao, 1.f);
  final_ln_k<<<4096, 256, 0, stream>>>(query, ao, lng, lnb, out);
}

// Round 6
// 342.610 us; speedup vs baseline: 1.6929x; 1.0909x over previous
//
#include <hip/hip_runtime.h>

#define B_ 4
#define LQ 1024
#define LK 2048
#define E_ 768
#define H_ 16
#define HD_ 48
#define HDP 64

// ---- output layout (flat floats in d_out) ----
#define OUT0_SIZE (B_*LQ*E_)
#define AW_OFF    (OUT0_SIZE)
#define AW_SIZE   (B_*LQ*LK)
#define NH_OFF    (AW_OFF + AW_SIZE)
#define SF_OFF    (NH_OFF + 4)
#define GV_OFF    (NH_OFF + 8)

// ---- workspace layout (bytes) ----
#define WOFF_PIN    0
#define WOFF_QFRAG  49152                                  // [bh][LQ/16][2][64][8] bf16 (zeroed pad)
#define WOFF_KFRAG  (WOFF_QFRAG + (size_t)B_*H_*LQ*HDP*2)  // [bh][LK/16][2][64][8] bf16 (zeroed pad)
#define WOFF_VFRAG  (WOFF_KFRAG + (size_t)B_*H_*LK*HDP*2)  // [bh][LK/64][3][2][64][8] bf16
#define WOFF_CTX    (WOFF_VFRAG + (size_t)B_*H_*HD_*LK*2)  // ctx frag-major [m/16][24][64][8]
#define WOFF_DINV   (WOFF_CTX + (size_t)B_*LQ*E_*2)
#define WOFF_H1     (WOFF_DINV + (size_t)B_*H_*LQ*4)
#define WOFF_H2     (WOFF_H1 + B_*E_*4)
#define WOFF_WBF    (WOFF_H2 + B_*(E_/2)*4)                // ipw frag bf16 [144][24][64][8]
#define WOFF_OWBF   (WOFF_WBF + (size_t)2304*768*2)        // outw frag bf16 [48][24][64][8]
#define WOFF_AO     (WOFF_OWBF + (size_t)768*768*2)        // f32 [B*LQ][E]  (aliases VBF)
#define WOFF_VBF    WOFF_AO                                // value frag bf16 (dead before AO written)
#define WS_SMALL    (WOFF_AO + (size_t)B_*LQ*E_*4)
#define WOFF_QBF    WS_SMALL                               // query frag bf16
#define WOFF_KBF    (WOFF_QBF + (size_t)B_*LQ*E_*2)        // key frag bf16
#define WS_FULL     (WOFF_KBF + (size_t)B_*LK*E_*2)
#define WS_ZERO_BYTES WOFF_VFRAG

typedef unsigned short u16;
typedef __attribute__((ext_vector_type(8))) short short8;
typedef __attribute__((ext_vector_type(4))) short short4v;
typedef __attribute__((ext_vector_type(4))) float floatx4;

#define SC2 0.20823506544914194f
#define MFMA16(a,b,c) __builtin_amdgcn_mfma_f32_16x16x32_bf16(a,b,c,0,0,0)

__device__ __forceinline__ u16 f2bf(float x) {
  union { float f; unsigned u; } v; v.f = x;
  unsigned r = v.u + 0x7fffu + ((v.u >> 16) & 1u);
  return (u16)(r >> 16);
}
// HW packed f32->bf16 (RNE): 1 instr replaces ~8 ops of manual rounding+pack.
__device__ __forceinline__ unsigned cvt_pk_bf16(float a, float b) {
  unsigned r;
  asm("v_cvt_pk_bf16_f32 %0, %1, %2" : "=v"(r) : "v"(a), "v"(b));
  return r;
}
__device__ __forceinline__ short8 ldfrag_f32(const float* p) {
  const float4* q4 = (const float4*)p;
  float4 a = q4[0], b = q4[1];
  short8 r;
  r[0]=(short)f2bf(a.x); r[1]=(short)f2bf(a.y); r[2]=(short)f2bf(a.z); r[3]=(short)f2bf(a.w);
  r[4]=(short)f2bf(b.x); r[5]=(short)f2bf(b.y); r[6]=(short)f2bf(b.z); r[7]=(short)f2bf(b.w);
  return r;
}
__device__ __forceinline__ short8 ldfrag_bf16(const u16* p) { return *(const short8*)p; }

__device__ __forceinline__ size_t qkfrag_idx(int bh, int ltiles, int tile,
                                             int half, int slot, int e) {
  return ((((size_t)bh*ltiles + tile)*2 + half)*64 + slot)*8 + e;
}

// ---- f32 [R][768] row-major -> bf16 fragment-major [R/16][24][64][8] -------
__global__ __launch_bounds__(256) void conv_frag_k(const float* __restrict__ src,
                                                   u16* __restrict__ dst) {
  __shared__ u16 ls[16][776];  // +8 pad: row stride 388 dw == 4 mod 32 banks
  int tid = threadIdx.x;
  size_t base = (size_t)blockIdx.x * 16 * 768;
  #pragma unroll
  for (int j=0;j<12;j++) {
    int i4 = tid + j*256;               // 3072 float4s
    int r = i4 / 192, c4 = i4 - r*192;
    float4 v = *(const float4*)(src + base + (size_t)r*768 + c4*4);
    ushort4 o;
    o.x = f2bf(v.x); o.y = f2bf(v.y); o.z = f2bf(v.z); o.w = f2bf(v.w);
    *(ushort4*)&ls[r][c4*4] = o;
  }
  __syncthreads();
  u16* db = dst + (size_t)blockIdx.x * 24 * 512;
  #pragma unroll
  for (int j=0;j<6;j++) {
    int cid = tid + j*256;              // 1536 chunks of 8
    int kt = cid >> 6, slot = cid & 63;
    int rr = slot & 15, qq = slot >> 4;
    *(short8*)(db + (size_t)(kt*64 + slot)*8) = *(const short8*)&ls[rr][kt*32 + qq*8];
  }
}

// ---- mask -> fragment pad slots ---------------------------------------------
// qfrag pad slot d=48 := 1.0 for every q row; kfrag pad slot d=48 := -1e30 for
// masked k rows. QK^T then accumulates -1e30 into masked scores via MFMA, so
// exp2 underflows to exactly 0 -- removes all per-score mask ops from both
// attention kernels. (d=48: half=1, quad=2, e=0; other pad slots stay zero.)
__global__ __launch_bounds__(256) void maskpad_k(const unsigned char* __restrict__ mask,
    u16* __restrict__ qfrag, u16* __restrict__ kfrag) {
  int tid = blockIdx.x*256 + threadIdx.x;            // 131072 threads
  if (tid < B_*H_*LQ) {
    int bh = tid >> 10, row = tid & (LQ-1);
    qfrag[qkfrag_idx(bh, LQ/16, row>>4, 1, 32 + (row&15), 0)] = 0x3F80; // bf16(1.0)
  }
  int bh = tid >> 11, row = tid & (LK-1);
  if (mask[(size_t)(bh>>4)*LK + row])
    kfrag[qkfrag_idx(bh, LK/16, row>>4, 1, 32 + (row&15), 0)] = f2bf(-1e30f);
}

// ---------------- pooling: float4 columns, 16-row slices, deep TLP -----------
// R5 lesson: 1.1 wave/SIMD + scalar stride-3KB loads = latency-bound 62us at
// 307 GB/s. Now: 192 threads own the 192 float4 feature-columns (1KB/wave
// coalesced rows), 16-row slices -> 768 blocks (9 waves/CU), 16 independent
// float4 loads fully unrolled and in flight before first use.
__global__ __launch_bounds__(192) void pool_k(const float* __restrict__ query,
                                              const float* __restrict__ key,
                                              float* __restrict__ pin) {
  int bid = blockIdx.x;
  const float* src; int fofs, b;
  if (bid < 256) { b = bid >> 6; int sl = bid & 63;
    src = query + ((size_t)b*LQ + sl*16)*E_; fofs = 0; }
  else { int id = bid - 256; b = id >> 7; int sl = id & 127;
    src = key + ((size_t)b*LK + sl*16)*E_; fofs = E_; }
  int t = threadIdx.x;
  const float4* p = (const float4*)src + t;
  float4 s = {0.f,0.f,0.f,0.f};
  #pragma unroll
  for (int i=0;i<16;i++) {
    float4 v = p[(size_t)i*192];
    s.x += v.x; s.y += v.y; s.z += v.z; s.w += v.w;
  }
  float* d = &pin[b*2*E_ + fofs + t*4];
  atomicAdd(d+0, s.x); atomicAdd(d+1, s.y);
  atomicAdd(d+2, s.z); atomicAdd(d+3, s.w);
}

// ---------------- MLP head, fp32 ---------------------------------------------
__global__ __launch_bounds__(256) void mlp1_k(const float* __restrict__ pin,
    const float* __restrict__ Wp1, const float* __restrict__ bp1,
    float* __restrict__ h1) {
  __shared__ float sp[B_][2*E_];
  int tid = threadIdx.x;
  for (int j = tid; j < B_*2*E_; j += 256) {
    int c = j % (2*E_);
    sp[j/(2*E_)][c] = pin[j] * (c < E_ ? (1.f/LQ) : (1.f/LK));
  }
  __syncthreads();
  int wv = tid >> 6, lane = tid & 63;
  int r = blockIdx.x*4 + wv;                       // grid 192 -> rows 0..767
  const float4* w4 = (const float4*)(Wp1 + (size_t)r*(2*E_));
  float4 wreg[6];
  #pragma unroll
  for (int u=0;u<6;u++) wreg[u] = w4[lane + u*64]; // 384 float4 per row
  float a[B_] = {0.f,0.f,0.f,0.f};
  #pragma unroll
  for (int u=0;u<6;u++)
    #pragma unroll
    for (int b=0;b<B_;b++) {
      float4 s4 = *(const float4*)&sp[b][(lane + u*64)*4];
      a[b] += wreg[u].x*s4.x + wreg[u].y*s4.y + wreg[u].z*s4.z + wreg[u].w*s4.w;
    }
  #pragma unroll
  for (int m=1;m<64;m<<=1)
    #pragma unroll
    for (int b=0;b<B_;b++) a[b] += __shfl_xor(a[b], m, 64);
  if (lane == 0) {
    float bb = bp1[r];
    #pragma unroll
    for (int b=0;b<B_;b++) h1[b*E_ + r] = fmaxf(a[b]+bb, 0.f);
  }
}

__global__ __launch_bounds__(256) void mlp2_k(const float* __restrict__ h1,
    const float* __restrict__ Wp2, const float* __restrict__ bp2,
    float* __restrict__ h2) {
  __shared__ float sh[B_][E_];
  int tid = threadIdx.x;
  for (int j = tid; j < B_*E_; j += 256) sh[j/E_][j%E_] = h1[j];
  __syncthreads();
  int wv = tid >> 6, lane = tid & 63;
  int r = blockIdx.x*4 + wv;                       // grid 96 -> rows 0..383
  const float4* w4 = (const float4*)(Wp2 + (size_t)r*E_);
  float4 wreg[3];
  #pragma unroll
  for (int u=0;u<3;u++) wreg[u] = w4[lane + u*64]; // 192 float4 per row
  float a[B_] = {0.f,0.f,0.f,0.f};
  #pragma unroll
  for (int u=0;u<3;u++)
    #pragma unroll
    for (int b=0;b<B_;b++) {
      float4 s4 = *(const float4*)&sh[b][(lane + u*64)*4];
      a[b] += wreg[u].x*s4.x + wreg[u].y*s4.y + wreg[u].z*s4.z + wreg[u].w*s4.w;
    }
  #pragma unroll
  for (int m=1;m<64;m<<=1)
    #pragma unroll
    for (int b=0;b<B_;b++) a[b] += __shfl_xor(a[b], m, 64);
  if (lane == 0) {
    float bb = bp2[r];
    #pragma unroll
    for (int b=0;b<B_;b++) h2[b*(E_/2) + r] = fmaxf(a[b]+bb, 0.f);
  }
}

__global__ __launch_bounds__(256) void mlp3_k(const float* __restrict__ h2,
    const float* __restrict__ Wp3, const float* __restrict__ bp3,
    float* __restrict__ out) {
  int tid = threadIdx.x, wv = tid >> 6, lane = tid & 63;
  float a0=0.f,a1=0.f,a2=0.f;
  #pragma unroll
  for (int u=0;u<6;u++) {
    int i = lane + u*64;
    float x = h2[wv*(E_/2)+i];
    a0 += x*Wp3[i]; a1 += x*Wp3[(E_/2)+i]; a2 += x*Wp3[2*(E_/2)+i];
  }
  #pragma unroll
  for (int m=1;m<64;m<<=1){
    a0+=__shfl_xor(a0,m,64); a1+=__shfl_xor(a1,m,64); a2+=__shfl_xor(a2,m,64);
  }
  if (lane == 0) {
    float p0 = a0 + bp3[0], p1 = a1 + bp3[1], p2 = a2 + bp3[2];
    float s0 = 1.f/(1.f+expf(-p0));
    float s1 = 1.f/(1.f+expf(-p1));
    float s2 = 1.f/(1.f+expf(-p2));
    out[NH_OFF + wv] = rintf(s0*(H_-1) + 1.f);
    out[SF_OFF + wv] = s1*0.5f + 0.5f;
    out[GV_OFF + wv] = s2;
  }
}

// ---- 128m x 64n GEMM, frag-major bf16 operands, XCD-chunked dispatch --------
// C[m][n] = (sum_k A[m][k]*B[n][k] + bias[n]) * cscale
// cscale folds the 1/sqrt(HD)*log2(e) softmax scale into qfrag (1.0 elsewhere).
template<int MODE, bool ABF, int TSH>
__global__ __launch_bounds__(256) void gemm_fm(const void* __restrict__ Ap,
    const u16* __restrict__ Bf, const float* __restrict__ bias,
    void* __restrict__ Cp, float cscale) {
  int lane = threadIdx.x & 63, wv = threadIdx.x >> 6;
  int lc = lane & 15, quad = lane >> 4;
  int lid = blockIdx.y * gridDim.x + blockIdx.x;
  int xcd = lid & 7, rr = lid >> 3;
  int C = gridDim.y >> 3;
  int lx = rr % gridDim.x, ly = xcd*C + rr / gridDim.x;
  int wm = ly*128 + (wv & 1)*64;
  int wn = lx*64  + (wv >> 1)*32;
  int mt0 = wm >> 4, nt0 = wn >> 4;
  const float* Af = (const float*)Ap;
  const u16*  Abf = (const u16*)Ap;
  floatx4 acc[4][2];
  #pragma unroll
  for (int s=0;s<4;s++)
    #pragma unroll
    for (int t=0;t<2;t++) acc[s][t] = (floatx4){0.f,0.f,0.f,0.f};
  #pragma unroll 2
  for (int kt=0; kt<24; kt++) {
    short8 af[4], bf2[2];
    #pragma unroll
    for (int s=0;s<4;s++)
      af[s] = ABF ? ldfrag_bf16(Abf + ((size_t)(mt0+s)*24 + kt)*512 + lane*8)
                  : ldfrag_f32(Af + (size_t)(wm + s*16 + lc)*E_ + kt*32 + quad*8);
    #pragma unroll
    for (int t=0;t<2;t++)
      bf2[t] = ldfrag_bf16(Bf + ((size_t)(nt0+t)*24 + kt)*512 + lane*8);
    #pragma unroll
    for (int s=0;s<4;s++)
      #pragma unroll
      for (int t=0;t<2;t++)
        acc[s][t] = MFMA16(af[s], bf2[t], acc[s][t]);
  }
  #pragma unroll
  for (int s=0;s<4;s++)
    #pragma unroll
    for (int t=0;t<2;t++)
      #pragma unroll
      for (int r=0;r<4;r++) {
        int m = wm + s*16 + quad*4 + r;
        int n = wn + t*16 + lc;
        float v = (acc[s][t][r] + bias[n]) * cscale;
        if (MODE == 0) {
          ((float*)Cp)[(size_t)m*E_ + n] = v;
        } else if (MODE == 1) {
          int bi = m >> TSH, l = m & ((1<<TSH)-1);
          int hh = n / HD_, d = n - hh*HD_;
          int half = d >> 5, q2 = (d >> 3) & 3, e = d & 7;
          ((u16*)Cp)[qkfrag_idx(bi*H_+hh, (1<<TSH)>>4, l>>4, half, q2*16 + (l&15), e)]
            = f2bf(v);
        } else {
          int bi = m >> 11, kc = m & 2047;
          int hh = n / HD_, d = n - hh*HD_;
          int dt = d >> 4, nn = d & 15;
          int kt2 = kc >> 6, c0 = (kc >> 5) & 1, q2 = (kc >> 3) & 3, e = kc & 7;
          size_t idx = ((((size_t)(bi*H_+hh)*(LK/64) + kt2)*3 + dt)*2 + c0)*512
                       + (q2*16+nn)*8 + e;
          ((u16*)Cp)[idx] = f2bf(v);
        }
      }
}

// ---- fused attention: 8 waves, k-split in 2 halves, LDS combine -------------
// waves 0-3: k in [0,1024), waves 4-7: k in [1024,2048) for the same 128 q rows.
// Doubles waves/SIMD (2->4) at unchanged per-block K/V cache traffic.
// Mask + softmax scale pre-folded into fragments (see maskpad_k / gemm cscale).
__global__ __launch_bounds__(512) void attn_fused_k(const u16* __restrict__ qfrag,
    const u16* __restrict__ kfrag, const u16* __restrict__ vfrag,
    float* __restrict__ dinv, u16* __restrict__ ctxb) {
  __shared__ __align__(16) u16 lp[8][16][72];
  __shared__ float cacc[4][64][33];   // stride 33: bank = lane mod 32 -> 2-way (free)
  int lane = threadIdx.x & 63, wv = threadIdx.x >> 6;
  int wq = wv & 3, kw = wv >> 2;
  int lc = lane & 15, quad = lane >> 4;
  int b = blockIdx.z, h = blockIdx.y, bh = b*H_ + h;
  int qw0 = blockIdx.x*128 + wq*32;
  const u16* qb = qfrag + (size_t)bh*(LQ/16)*1024;
  const u16* kb = kfrag + (size_t)bh*(LK/16)*1024;
  const u16* vb = vfrag + (size_t)bh*(LK/64)*3072;
  short8 qf[2][2];
  #pragma unroll
  for (int qt=0;qt<2;qt++)
    #pragma unroll
    for (int hf=0;hf<2;hf++)
      qf[qt][hf] = ldfrag_bf16(qb + (((qw0>>4)+qt)*2 + hf)*512 + lane*8);
  floatx4 lv[2];
  lv[0] = (floatx4){0.f,0.f,0.f,0.f}; lv[1] = lv[0];
  floatx4 acc[2][3];
  #pragma unroll
  for (int qt=0;qt<2;qt++)
    #pragma unroll
    for (int dt=0;dt<3;dt++) acc[qt][dt] = (floatx4){0.f,0.f,0.f,0.f};

  int kend = (kw + 1) << 10;
  for (int k0 = kw << 10; k0 < kend; k0 += 64) {
    short8 kf[4][2];
    #pragma unroll
    for (int t=0;t<4;t++)
      #pragma unroll
      for (int hf=0;hf<2;hf++)
        kf[t][hf] = ldfrag_bf16(kb + (((k0>>4)+t)*2 + hf)*512 + lane*8);
    short8 vf[2][3];
    #pragma unroll
    for (int c0=0;c0<2;c0++)
      #pragma unroll
      for (int dt=0;dt<3;dt++)
        vf[c0][dt] = ldfrag_bf16(vb + (((k0>>6)*3 + dt)*2 + c0)*512 + lane*8);

    #pragma unroll
    for (int qt=0;qt<2;qt++) {
      #pragma unroll
      for (int t=0;t<4;t++) {
        floatx4 z = {0.f,0.f,0.f,0.f};
        floatx4 st = MFMA16(kf[t][0], qf[qt][0], MFMA16(kf[t][1], qf[qt][1], z));
        floatx4 p;
        #pragma unroll
        for (int r=0;r<4;r++) p[r] = __builtin_amdgcn_exp2f(st[r]);
        lv[qt] += p;                       // 4 independent accum chains
        uint2 pk2;
        pk2.x = cvt_pk_bf16(p[0], p[1]);
        pk2.y = cvt_pk_bf16(p[2], p[3]);
        *(uint2*)&lp[wv][lc][t*16 + quad*4] = pk2;
      }
      short8 pa0 = *(const short8*)&lp[wv][lc][quad*8];
      short8 pa1 = *(const short8*)&lp[wv][lc][32 + quad*8];
      #pragma unroll
      for (int dt=0;dt<3;dt++)
        acc[qt][dt] = MFMA16(pa1, vf[1][dt], MFMA16(pa0, vf[0][dt], acc[qt][dt]));
    }
  }
  float l0 = lv[0][0]+lv[0][1]+lv[0][2]+lv[0][3];
  float l1 = lv[1][0]+lv[1][1]+lv[1][2]+lv[1][3];
  if (kw) {                               // upper half: publish partials
    float* cb = &cacc[wq][lane][0];
    #pragma unroll
    for (int qt=0;qt<2;qt++)
      #pragma unroll
      for (int dt=0;dt<3;dt++)
        #pragma unroll
        for (int r=0;r<4;r++) cb[(qt*3+dt)*4 + r] = acc[qt][dt][r];
    cb[24] = l0; cb[25] = l1;
  }
  __syncthreads();
  if (kw) return;
  {                                       // lower half: combine
    const float* cb = &cacc[wq][lane][0];
    #pragma unroll
    for (int qt=0;qt<2;qt++)
      #pragma unroll
      for (int dt=0;dt<3;dt++)
        #pragma unroll
        for (int r=0;r<4;r++) acc[qt][dt][r] += cb[(qt*3+dt)*4 + r];
    l0 += cb[24]; l1 += cb[25];
  }
  float lq[2] = {l0, l1};
  #pragma unroll
  for (int qt=0;qt<2;qt++) {
    float s = lq[qt];
    s += __shfl_xor(s, 16, 64);
    s += __shfl_xor(s, 32, 64);
    float linv = 1.f/s;
    if (lane < 16) dinv[(size_t)bh*LQ + qw0 + qt*16 + lane] = linv;
    float li[4];
    #pragma unroll
    for (int r=0;r<4;r++) li[r] = __shfl(linv, quad*4 + r, 64);
    #pragma unroll
    for (int dt=0;dt<3;dt++)
      #pragma unroll
      for (int r=0;r<4;r++) {
        int mg = b*LQ + qw0 + qt*16 + quad*4 + r;
        int k  = h*HD_ + dt*16 + lc;
        size_t idx = (((size_t)(mg>>4)*(E_/32) + (k>>5))*64 + ((k>>3)&3)*16 + (mg&15))*8 + (k&7);
        ctxb[idx] = f2bf(acc[qt][dt][r]*li[r]);
      }
  }
}

// ---- attn_weights: 128q x 128k block tile, LDS-staged heads, dbuf -----------
#define AW_QSTR ((LQ/16)*1024)   // u16 elems per head in qfrag
#define AW_KSTR ((LK/16)*1024)   // u16 elems per head in kfrag

__global__ __launch_bounds__(512) void attn_weights_k(const u16* __restrict__ qfrag,
    const u16* __restrict__ kfrag, const float* __restrict__ dinv,
    float* __restrict__ aw) {
  __shared__ __align__(16) u16 sq[2][8192];   // [buf][tile(8)][half(2)][64][8]
  __shared__ __align__(16) u16 sk[2][8192];
  int tid = threadIdx.x;
  int lane = tid & 63, wv = tid >> 6;
  int lc = lane & 15, quad = lane >> 4;
  int xcd = blockIdx.x & 7, rest = blockIdx.x >> 3;
  int kx = rest & 15, g3 = rest >> 4;          // kx: k-block 0..15, g3: 0..3
  int y = xcd, b = g3;                         // q-band 0..7, batch 0..3
  int qblk = y*128, kblk = kx*128;
  int wq = wv & 1, wk = wv >> 1;               // wave tile: 64q x 32k
  int qw0 = qblk + wq*64;
  int k0  = kblk + wk*32;
  const u16* qb0 = qfrag + (size_t)(b*H_)*AW_QSTR + (qblk>>4)*1024;
  const u16* kb0 = kfrag + (size_t)(b*H_)*AW_KSTR + (kblk>>4)*1024;
  const float* dv0 = dinv + (size_t)(b*H_)*LQ + qw0;
  floatx4 acc[4][2];
  #pragma unroll
  for (int qt=0;qt<4;qt++)
    #pragma unroll
    for (int t=0;t<2;t++) acc[qt][t] = (floatx4){0.f,0.f,0.f,0.f};

  short8 gq[2], gk[2];
  #pragma unroll
  for (int i=0;i<2;i++) {
    gq[i] = *(const short8*)(qb0 + (size_t)(tid + i*512)*8);
    gk[i] = *(const short8*)(kb0 + (size_t)(tid + i*512)*8);
  }
  #pragma unroll
  for (int i=0;i<2;i++) {
    *(short8*)&sq[0][(tid + i*512)*8] = gq[i];
    *(short8*)&sk[0][(tid + i*512)*8] = gk[i];
  }
  __syncthreads();

  for (int h=0; h<H_; h++) {
    int cur = h & 1;
    if (h+1 < H_) {                      // issue next head's loads early
      const u16* qbn = qb0 + (size_t)(h+1)*AW_QSTR;
      const u16* kbn = kb0 + (size_t)(h+1)*AW_KSTR;
      #pragma unroll
      for (int i=0;i<2;i++) {
        gq[i] = *(const short8*)(qbn + (size_t)(tid + i*512)*8);
        gk[i] = *(const short8*)(kbn + (size_t)(tid + i*512)*8);
      }
    }
    float di[4];
    const float* dvh = dv0 + (size_t)h*LQ;
    #pragma unroll
    for (int qt=0;qt<4;qt++) di[qt] = dvh[qt*16 + lc];
    short8 kf[2][2];
    #pragma unroll
    for (int t=0;t<2;t++)
      #pragma unroll
      for (int hf=0;hf<2;hf++)
        kf[t][hf] = *(const short8*)&sk[cur][(((wk*2+t)*2+hf)*64 + lane)*8];
    #pragma unroll
    for (int qt=0;qt<4;qt++) {
      short8 qf0 = *(const short8*)&sq[cur][(((wq*4+qt)*2+0)*64 + lane)*8];
      short8 qf1 = *(const short8*)&sq[cur][(((wq*4+qt)*2+1)*64 + lane)*8];
      #pragma unroll
      for (int t=0;t<2;t++) {
        floatx4 z = {0.f,0.f,0.f,0.f};
        floatx4 st = MFMA16(kf[t][0], qf0, MFMA16(kf[t][1], qf1, z));
        #pragma unroll
        for (int r=0;r<4;r++)
          acc[qt][t][r] += __builtin_amdgcn_exp2f(st[r]) * di[qt];
      }
    }
    __syncthreads();                     // all waves done reading buf cur
    if (h+1 < H_) {
      int nxt = cur ^ 1;
      #pragma unroll
      for (int i=0;i<2;i++) {
        *(short8*)&sq[nxt][(tid + i*512)*8] = gq[i];
        *(short8*)&sk[nxt][(tid + i*512)*8] = gk[i];
      }
    }
    __syncthreads();                     // writes visible for next head
  }
  const float inv16 = 1.f/16.f;
  #pragma unroll
  for (int qt=0;qt<4;qt++)
    #pragma unroll
    for (int t=0;t<2;t++) {
      floatx4 v = acc[qt][t];
      v[0]*=inv16; v[1]*=inv16; v[2]*=inv16; v[3]*=inv16;
      *(floatx4*)&aw[((size_t)b*LQ + qw0 + qt*16 + lc)*LK + k0 + t*16 + quad*4] = v;
    }
}

// ---------------- fused gate + residual + layernorm --------------------------
__global__ __launch_bounds__(256) void final_ln_k(const float* __restrict__ query,
    const float* __restrict__ ao, const float* __restrict__ lng,
    const float* __restrict__ lnb, float* __restrict__ out) {
  int row = blockIdx.x, b = row >> 10, tid = threadIdx.x;
  float sf = out[SF_OFF + b];
  float gv = out[GV_OFF + b];
  float c1 = 2.f - gv, c2 = sf*gv;
  const float* q = query + (size_t)row*E_;
  const float* a = ao + (size_t)row*E_;
  float x[3], s1 = 0.f, s2 = 0.f;
  #pragma unroll
  for (int i=0;i<3;i++){ int j = tid + i*256; float v = q[j]*c1 + a[j]*c2; x[i]=v; s1+=v; s2+=v*v; }
  #pragma unroll
  for (int m=1;m<64;m<<=1){ s1 += __shfl_xor(s1,m,64); s2 += __shfl_xor(s2,m,64); }
  __shared__ float r1[4], r2[4];
  int wv = tid >> 6;
  if ((tid & 63) == 0){ r1[wv]=s1; r2[wv]=s2; }
  __syncthreads();
  s1 = r1[0]+r1[1]+r1[2]+r1[3];
  s2 = r2[0]+r2[1]+r2[2]+r2[3];
  float mu = s1*(1.f/E_);
  float var = s2*(1.f/E_) - mu*mu;
  float rs = rsqrtf(var + 1e-5f);
  #pragma unroll
  for (int i=0;i<3;i++){ int j = tid + i*256; out[(size_t)row*E_ + j] = (x[i]-mu)*rs*lng[j] + lnb[j]; }
}

extern "C" void kernel_launch(void* const* d_in, const int* in_sizes, int n_in,
                              void* d_out, int out_size, void* d_ws, size_t ws_size,
                              hipStream_t stream) {
  const float* query = (const float*)d_in[0];
  const float* key   = (const float*)d_in[1];
  const float* value = (const float*)d_in[2];
  const unsigned char* mask = (const unsigned char*)d_in[3];
  const float* Wp1 = (const float*)d_in[4];
  const float* bp1 = (const float*)d_in[5];
  const float* Wp2 = (const float*)d_in[6];
  const float* bp2 = (const float*)d_in[7];
  const float* Wp3 = (const float*)d_in[8];
  const float* bp3 = (const float*)d_in[9];
  const float* ipw = (const float*)d_in[10];
  const float* ipb = (const float*)d_in[11];
  const float* outw = (const float*)d_in[12];
  const float* outb = (const float*)d_in[13];
  const float* lng = (const float*)d_in[14];
  const float* lnb = (const float*)d_in[15];
  float* out = (float*)d_out;
  char* ws = (char*)d_ws;
  if (ws_size < WS_SMALL) return;
  bool full = (ws_size >= WS_FULL);
  float* pin  = (float*)(ws + WOFF_PIN);
  u16* qfrag  = (u16*)(ws + WOFF_QFRAG);
  u16* kfrag  = (u16*)(ws + WOFF_KFRAG);
  u16* vfrag  = (u16*)(ws + WOFF_VFRAG);
  u16* ctxb   = (u16*)(ws + WOFF_CTX);
  float* dinv = (float*)(ws + WOFF_DINV);
  float* h1   = (float*)(ws + WOFF_H1);
  float* h2   = (float*)(ws + WOFF_H2);
  u16* wbf    = (u16*)(ws + WOFF_WBF);
  u16* owbf   = (u16*)(ws + WOFF_OWBF);
  float* ao   = (float*)(ws + WOFF_AO);
  u16* vbf    = (u16*)(ws + WOFF_VBF);   // aliases ao (dead before ao written)
  u16* qbf    = (u16*)(ws + WOFF_QBF);
  u16* kbf    = (u16*)(ws + WOFF_KBF);

  hipMemsetAsync(ws, 0, WS_ZERO_BYTES, stream);  // pin + q/k frag padding
  maskpad_k<<<512, 256, 0, stream>>>(mask, qfrag, kfrag);
  pool_k<<<768, 192, 0, stream>>>(query, key, pin);
  mlp1_k<<<192, 256, 0, stream>>>(pin, Wp1, bp1, h1);
  mlp2_k<<<96, 256, 0, stream>>>(h1, Wp2, bp2, h2);
  mlp3_k<<<1, 256, 0, stream>>>(h2, Wp3, bp3, out);

  conv_frag_k<<<144, 256, 0, stream>>>(ipw, wbf);
  conv_frag_k<<<48, 256, 0, stream>>>(outw, owbf);
  const u16* wq = wbf;
  const u16* wk = wbf + (size_t)48*24*512;
  const u16* wvv = wbf + (size_t)96*24*512;
  if (full) {
    conv_frag_k<<<256, 256, 0, stream>>>(query, qbf);
    conv_frag_k<<<512, 256, 0, stream>>>(key, kbf);
    conv_frag_k<<<512, 256, 0, stream>>>(value, vbf);
    gemm_fm<1,true,10><<<dim3(12,32), 256, 0, stream>>>((const void*)qbf, wq, ipb, (void*)qfrag, SC2);
    gemm_fm<1,true,11><<<dim3(12,64), 256, 0, stream>>>((const void*)kbf, wk, ipb + E_, (void*)kfrag, 1.f);
    gemm_fm<2,true,11><<<dim3(12,64), 256, 0, stream>>>((const void*)vbf, wvv, ipb + 2*E_, (void*)vfrag, 1.f);
  } else {
    gemm_fm<1,false,10><<<dim3(12,32), 256, 0, stream>>>((const void*)query, wq, ipb, (void*)qfrag, SC2);
    gemm_fm<1,false,11><<<dim3(12,64), 256, 0, stream>>>((const void*)key, wk, ipb + E_, (void*)kfrag, 1.f);
    gemm_fm<2,false,11><<<dim3(12,64), 256, 0, stream>>>((const void*)value, wvv, ipb + 2*E_, (void*)vfrag, 1.f);
  }
  attn_fused_k<<<dim3(8,16,4), 512, 0, stream>>>(qfrag, kfrag, vfrag, dinv, ctxb);
  attn_weights_k<<<512, 512, 0, stream>>>(qfrag, kfrag, dinv, out + AW_OFF);
  gemm_fm<0,true,10><<<dim3(12,32), 256, 0, stream>>>((const void*)ctxb, owbf, outb, (void*)ao, 1.f);
  final_ln_k<<<4096, 256, 0, stream>>>(query, ao, lng, lnb, out);
}

// Round 7
// 339.339 us; speedup vs baseline: 1.7092x; 1.0096x over previous
//
#include <hip/hip_runtime.h>

#define B_ 4
#define LQ 1024
#define LK 2048
#define E_ 768
#define H_ 16
#define HD_ 48
#define HDP 64

// ---- output layout (flat floats in d_out) ----
#define OUT0_SIZE (B_*LQ*E_)
#define AW_OFF    (OUT0_SIZE)
#define AW_SIZE   (B_*LQ*LK)
#define NH_OFF    (AW_OFF + AW_SIZE)
#define SF_OFF    (NH_OFF + 4)
#define GV_OFF    (NH_OFF + 8)

// ---- workspace layout (bytes) ----
#define WOFF_PIN    0
#define WOFF_QFRAG  49152                                  // [bh][LQ/16][2][64][8] bf16 (zeroed pad)
#define WOFF_KFRAG  (WOFF_QFRAG + (size_t)B_*H_*LQ*HDP*2)  // [bh][LK/16][2][64][8] bf16 (zeroed pad)
#define WOFF_VFRAG  (WOFF_KFRAG + (size_t)B_*H_*LK*HDP*2)  // [bh][LK/64][3][2][64][8] bf16
#define WOFF_CTX    (WOFF_VFRAG + (size_t)B_*H_*HD_*LK*2)  // ctx frag-major [m/16][24][64][8]
#define WOFF_DINV   (WOFF_CTX + (size_t)B_*LQ*E_*2)
#define WOFF_H1     (WOFF_DINV + (size_t)B_*H_*LQ*4)
#define WOFF_H2     (WOFF_H1 + B_*E_*4)
#define WOFF_WBF    (WOFF_H2 + B_*(E_/2)*4)                // ipw frag bf16 [144][24][64][8]
#define WOFF_OWBF   (WOFF_WBF + (size_t)2304*768*2)        // outw frag bf16 [48][24][64][8]
#define WOFF_AO     (WOFF_OWBF + (size_t)768*768*2)        // f32 [B*LQ][E]  (aliases VBF)
#define WOFF_VBF    WOFF_AO                                // value frag bf16 (dead before AO written)
#define WS_SMALL    (WOFF_AO + (size_t)B_*LQ*E_*4)
#define WOFF_QBF    WS_SMALL                               // query frag bf16
#define WOFF_KBF    (WOFF_QBF + (size_t)B_*LQ*E_*2)        // key frag bf16
#define WS_FULL     (WOFF_KBF + (size_t)B_*LK*E_*2)
#define WS_ZERO_BYTES WOFF_VFRAG

typedef unsigned short u16;
typedef __attribute__((ext_vector_type(8))) short short8;
typedef __attribute__((ext_vector_type(4))) short short4v;
typedef __attribute__((ext_vector_type(4))) float floatx4;

#define SC2 0.20823506544914194f
#define MFMA16(a,b,c) __builtin_amdgcn_mfma_f32_16x16x32_bf16(a,b,c,0,0,0)

__device__ __forceinline__ u16 f2bf(float x) {
  union { float f; unsigned u; } v; v.f = x;
  unsigned r = v.u + 0x7fffu + ((v.u >> 16) & 1u);
  return (u16)(r >> 16);
}
// HW packed f32->bf16 (RNE): 1 instr replaces ~8 ops of manual rounding+pack.
__device__ __forceinline__ unsigned cvt_pk_bf16(float a, float b) {
  unsigned r;
  asm("v_cvt_pk_bf16_f32 %0, %1, %2" : "=v"(r) : "v"(a), "v"(b));
  return r;
}
__device__ __forceinline__ short8 ldfrag_f32(const float* p) {
  const float4* q4 = (const float4*)p;
  float4 a = q4[0], b = q4[1];
  short8 r;
  r[0]=(short)f2bf(a.x); r[1]=(short)f2bf(a.y); r[2]=(short)f2bf(a.z); r[3]=(short)f2bf(a.w);
  r[4]=(short)f2bf(b.x); r[5]=(short)f2bf(b.y); r[6]=(short)f2bf(b.z); r[7]=(short)f2bf(b.w);
  return r;
}
__device__ __forceinline__ short8 ldfrag_bf16(const u16* p) { return *(const short8*)p; }

__device__ __forceinline__ size_t qkfrag_idx(int bh, int ltiles, int tile,
                                             int half, int slot, int e) {
  return ((((size_t)bh*ltiles + tile)*2 + half)*64 + slot)*8 + e;
}

// ---- f32 [R][768] row-major -> bf16 fragment-major [R/16][24][64][8] -------
__global__ __launch_bounds__(256) void conv_frag_k(const float* __restrict__ src,
                                                   u16* __restrict__ dst) {
  __shared__ u16 ls[16][776];  // +8 pad: row stride 388 dw == 4 mod 32 banks
  int tid = threadIdx.x;
  size_t base = (size_t)blockIdx.x * 16 * 768;
  #pragma unroll
  for (int j=0;j<12;j++) {
    int i4 = tid + j*256;               // 3072 float4s
    int r = i4 / 192, c4 = i4 - r*192;
    float4 v = *(const float4*)(src + base + (size_t)r*768 + c4*4);
    ushort4 o;
    o.x = f2bf(v.x); o.y = f2bf(v.y); o.z = f2bf(v.z); o.w = f2bf(v.w);
    *(ushort4*)&ls[r][c4*4] = o;
  }
  __syncthreads();
  u16* db = dst + (size_t)blockIdx.x * 24 * 512;
  #pragma unroll
  for (int j=0;j<6;j++) {
    int cid = tid + j*256;              // 1536 chunks of 8
    int kt = cid >> 6, slot = cid & 63;
    int rr = slot & 15, qq = slot >> 4;
    *(short8*)(db + (size_t)(kt*64 + slot)*8) = *(const short8*)&ls[rr][kt*32 + qq*8];
  }
}

// ---- mask -> fragment pad slots ---------------------------------------------
// qfrag pad slot d=48 := 1.0 for every q row; kfrag pad slot d=48 := -1e30 for
// masked k rows. QK^T then accumulates -1e30 into masked scores via MFMA, so
// exp2 underflows to exactly 0 -- removes all per-score mask ops from both
// attention kernels. (d=48: half=1, quad=2, e=0; other pad slots stay zero.)
__global__ __launch_bounds__(256) void maskpad_k(const unsigned char* __restrict__ mask,
    u16* __restrict__ qfrag, u16* __restrict__ kfrag) {
  int tid = blockIdx.x*256 + threadIdx.x;            // 131072 threads
  if (tid < B_*H_*LQ) {
    int bh = tid >> 10, row = tid & (LQ-1);
    qfrag[qkfrag_idx(bh, LQ/16, row>>4, 1, 32 + (row&15), 0)] = 0x3F80; // bf16(1.0)
  }
  int bh = tid >> 11, row = tid & (LK-1);
  if (mask[(size_t)(bh>>4)*LK + row])
    kfrag[qkfrag_idx(bh, LK/16, row>>4, 1, 32 + (row&15), 0)] = f2bf(-1e30f);
}

// ---------------- pooling: float4 columns, 16-row slices, deep TLP -----------
__global__ __launch_bounds__(192) void pool_k(const float* __restrict__ query,
                                              const float* __restrict__ key,
                                              float* __restrict__ pin) {
  int bid = blockIdx.x;
  const float* src; int fofs, b;
  if (bid < 256) { b = bid >> 6; int sl = bid & 63;
    src = query + ((size_t)b*LQ + sl*16)*E_; fofs = 0; }
  else { int id = bid - 256; b = id >> 7; int sl = id & 127;
    src = key + ((size_t)b*LK + sl*16)*E_; fofs = E_; }
  int t = threadIdx.x;
  const float4* p = (const float4*)src + t;
  float4 s = {0.f,0.f,0.f,0.f};
  #pragma unroll
  for (int i=0;i<16;i++) {
    float4 v = p[(size_t)i*192];
    s.x += v.x; s.y += v.y; s.z += v.z; s.w += v.w;
  }
  float* d = &pin[b*2*E_ + fofs + t*4];
  atomicAdd(d+0, s.x); atomicAdd(d+1, s.y);
  atomicAdd(d+2, s.z); atomicAdd(d+3, s.w);
}

// ---------------- MLP head, fp32 ---------------------------------------------
__global__ __launch_bounds__(256) void mlp1_k(const float* __restrict__ pin,
    const float* __restrict__ Wp1, const float* __restrict__ bp1,
    float* __restrict__ h1) {
  __shared__ float sp[B_][2*E_];
  int tid = threadIdx.x;
  for (int j = tid; j < B_*2*E_; j += 256) {
    int c = j % (2*E_);
    sp[j/(2*E_)][c] = pin[j] * (c < E_ ? (1.f/LQ) : (1.f/LK));
  }
  __syncthreads();
  int wv = tid >> 6, lane = tid & 63;
  int r = blockIdx.x*4 + wv;                       // grid 192 -> rows 0..767
  const float4* w4 = (const float4*)(Wp1 + (size_t)r*(2*E_));
  float4 wreg[6];
  #pragma unroll
  for (int u=0;u<6;u++) wreg[u] = w4[lane + u*64]; // 384 float4 per row
  float a[B_] = {0.f,0.f,0.f,0.f};
  #pragma unroll
  for (int u=0;u<6;u++)
    #pragma unroll
    for (int b=0;b<B_;b++) {
      float4 s4 = *(const float4*)&sp[b][(lane + u*64)*4];
      a[b] += wreg[u].x*s4.x + wreg[u].y*s4.y + wreg[u].z*s4.z + wreg[u].w*s4.w;
    }
  #pragma unroll
  for (int m=1;m<64;m<<=1)
    #pragma unroll
    for (int b=0;b<B_;b++) a[b] += __shfl_xor(a[b], m, 64);
  if (lane == 0) {
    float bb = bp1[r];
    #pragma unroll
    for (int b=0;b<B_;b++) h1[b*E_ + r] = fmaxf(a[b]+bb, 0.f);
  }
}

__global__ __launch_bounds__(256) void mlp2_k(const float* __restrict__ h1,
    const float* __restrict__ Wp2, const float* __restrict__ bp2,
    float* __restrict__ h2) {
  __shared__ float sh[B_][E_];
  int tid = threadIdx.x;
  for (int j = tid; j < B_*E_; j += 256) sh[j/E_][j%E_] = h1[j];
  __syncthreads();
  int wv = tid >> 6, lane = tid & 63;
  int r = blockIdx.x*4 + wv;                       // grid 96 -> rows 0..383
  const float4* w4 = (const float4*)(Wp2 + (size_t)r*E_);
  float4 wreg[3];
  #pragma unroll
  for (int u=0;u<3;u++) wreg[u] = w4[lane + u*64]; // 192 float4 per row
  float a[B_] = {0.f,0.f,0.f,0.f};
  #pragma unroll
  for (int u=0;u<3;u++)
    #pragma unroll
    for (int b=0;b<B_;b++) {
      float4 s4 = *(const float4*)&sh[b][(lane + u*64)*4];
      a[b] += wreg[u].x*s4.x + wreg[u].y*s4.y + wreg[u].z*s4.z + wreg[u].w*s4.w;
    }
  #pragma unroll
  for (int m=1;m<64;m<<=1)
    #pragma unroll
    for (int b=0;b<B_;b++) a[b] += __shfl_xor(a[b], m, 64);
  if (lane == 0) {
    float bb = bp2[r];
    #pragma unroll
    for (int b=0;b<B_;b++) h2[b*(E_/2) + r] = fmaxf(a[b]+bb, 0.f);
  }
}

__global__ __launch_bounds__(256) void mlp3_k(const float* __restrict__ h2,
    const float* __restrict__ Wp3, const float* __restrict__ bp3,
    float* __restrict__ out) {
  int tid = threadIdx.x, wv = tid >> 6, lane = tid & 63;
  float a0=0.f,a1=0.f,a2=0.f;
  #pragma unroll
  for (int u=0;u<6;u++) {
    int i = lane + u*64;
    float x = h2[wv*(E_/2)+i];
    a0 += x*Wp3[i]; a1 += x*Wp3[(E_/2)+i]; a2 += x*Wp3[2*(E_/2)+i];
  }
  #pragma unroll
  for (int m=1;m<64;m<<=1){
    a0+=__shfl_xor(a0,m,64); a1+=__shfl_xor(a1,m,64); a2+=__shfl_xor(a2,m,64);
  }
  if (lane == 0) {
    float p0 = a0 + bp3[0], p1 = a1 + bp3[1], p2 = a2 + bp3[2];
    float s0 = 1.f/(1.f+expf(-p0));
    float s1 = 1.f/(1.f+expf(-p1));
    float s2 = 1.f/(1.f+expf(-p2));
    out[NH_OFF + wv] = rintf(s0*(H_-1) + 1.f);
    out[SF_OFF + wv] = s1*0.5f + 0.5f;
    out[GV_OFF + wv] = s2;
  }
}

// ---- 128m x 64n GEMM, frag-major bf16 operands, XCD-chunked dispatch --------
// C[m][n] = (sum_k A[m][k]*B[n][k] + bias[n]) * cscale
// cscale folds the 1/sqrt(HD)*log2(e) softmax scale into qfrag (1.0 elsewhere).
template<int MODE, bool ABF, int TSH>
__global__ __launch_bounds__(256) void gemm_fm(const void* __restrict__ Ap,
    const u16* __restrict__ Bf, const float* __restrict__ bias,
    void* __restrict__ Cp, float cscale) {
  int lane = threadIdx.x & 63, wv = threadIdx.x >> 6;
  int lc = lane & 15, quad = lane >> 4;
  int lid = blockIdx.y * gridDim.x + blockIdx.x;
  int xcd = lid & 7, rr = lid >> 3;
  int C = gridDim.y >> 3;
  int lx = rr % gridDim.x, ly = xcd*C + rr / gridDim.x;
  int wm = ly*128 + (wv & 1)*64;
  int wn = lx*64  + (wv >> 1)*32;
  int mt0 = wm >> 4, nt0 = wn >> 4;
  const float* Af = (const float*)Ap;
  const u16*  Abf = (const u16*)Ap;
  floatx4 acc[4][2];
  #pragma unroll
  for (int s=0;s<4;s++)
    #pragma unroll
    for (int t=0;t<2;t++) acc[s][t] = (floatx4){0.f,0.f,0.f,0.f};
  #pragma unroll 2
  for (int kt=0; kt<24; kt++) {
    short8 af[4], bf2[2];
    #pragma unroll
    for (int s=0;s<4;s++)
      af[s] = ABF ? ldfrag_bf16(Abf + ((size_t)(mt0+s)*24 + kt)*512 + lane*8)
                  : ldfrag_f32(Af + (size_t)(wm + s*16 + lc)*E_ + kt*32 + quad*8);
    #pragma unroll
    for (int t=0;t<2;t++)
      bf2[t] = ldfrag_bf16(Bf + ((size_t)(nt0+t)*24 + kt)*512 + lane*8);
    #pragma unroll
    for (int s=0;s<4;s++)
      #pragma unroll
      for (int t=0;t<2;t++)
        acc[s][t] = MFMA16(af[s], bf2[t], acc[s][t]);
  }
  #pragma unroll
  for (int s=0;s<4;s++)
    #pragma unroll
    for (int t=0;t<2;t++)
      #pragma unroll
      for (int r=0;r<4;r++) {
        int m = wm + s*16 + quad*4 + r;
        int n = wn + t*16 + lc;
        float v = (acc[s][t][r] + bias[n]) * cscale;
        if (MODE == 0) {
          ((float*)Cp)[(size_t)m*E_ + n] = v;
        } else if (MODE == 1) {
          int bi = m >> TSH, l = m & ((1<<TSH)-1);
          int hh = n / HD_, d = n - hh*HD_;
          int half = d >> 5, q2 = (d >> 3) & 3, e = d & 7;
          ((u16*)Cp)[qkfrag_idx(bi*H_+hh, (1<<TSH)>>4, l>>4, half, q2*16 + (l&15), e)]
            = f2bf(v);
        } else {
          int bi = m >> 11, kc = m & 2047;
          int hh = n / HD_, d = n - hh*HD_;
          int dt = d >> 4, nn = d & 15;
          int kt2 = kc >> 6, c0 = (kc >> 5) & 1, q2 = (kc >> 3) & 3, e = kc & 7;
          size_t idx = ((((size_t)(bi*H_+hh)*(LK/64) + kt2)*3 + dt)*2 + c0)*512
                       + (q2*16+nn)*8 + e;
          ((u16*)Cp)[idx] = f2bf(v);
        }
      }
}

// ---- fused attention: 8 waves, k-split, XCD-grouped bh, aliased LDS ---------
// R6 lessons: (a) old grid put XCD = q-block index -> each XCD touched all 64
// bh's K/V (29MB >> 4MB L2) -> 118MB HBM fetch (3x unique). Now 1-D grid with
// bh = xcd*8 + (t>>3): each XCD owns 8 whole bh (K+V = 3.7MB, L2-resident).
// (b) lp (18.4KB) and cacc (33.8KB) were summed (52KB -> 3 blk/CU); lp is dead
// before cacc is written, so alias them in one 33.8KB buffer (+1 barrier)
// -> 4 blk/CU = 2048 thr/CU full residency.
__global__ __launch_bounds__(512) void attn_fused_k(const u16* __restrict__ qfrag,
    const u16* __restrict__ kfrag, const u16* __restrict__ vfrag,
    float* __restrict__ dinv, u16* __restrict__ ctxb) {
  __shared__ __align__(16) char smem[33792];
  u16 (*lp)[16][72] = (u16 (*)[16][72])smem;      // 8*16*72*2 = 18432 B
  float (*cacc)[64][33] = (float (*)[64][33])smem; // 4*64*33*4 = 33792 B (aliases lp)
  int lane = threadIdx.x & 63, wv = threadIdx.x >> 6;
  int wq = wv & 3, kw = wv >> 2;
  int lc = lane & 15, quad = lane >> 4;
  int xcd = blockIdx.x & 7, tt = blockIdx.x >> 3;
  int bh = xcd*8 + (tt >> 3), qx = tt & 7;        // 8 bh per XCD, q-blocks local
  int b = bh >> 4, h = bh & 15;
  int qw0 = qx*128 + wq*32;
  const u16* qb = qfrag + (size_t)bh*(LQ/16)*1024;
  const u16* kb = kfrag + (size_t)bh*(LK/16)*1024;
  const u16* vb = vfrag + (size_t)bh*(LK/64)*3072;
  short8 qf[2][2];
  #pragma unroll
  for (int qt=0;qt<2;qt++)
    #pragma unroll
    for (int hf=0;hf<2;hf++)
      qf[qt][hf] = ldfrag_bf16(qb + (((qw0>>4)+qt)*2 + hf)*512 + lane*8);
  floatx4 lv[2];
  lv[0] = (floatx4){0.f,0.f,0.f,0.f}; lv[1] = lv[0];
  floatx4 acc[2][3];
  #pragma unroll
  for (int qt=0;qt<2;qt++)
    #pragma unroll
    for (int dt=0;dt<3;dt++) acc[qt][dt] = (floatx4){0.f,0.f,0.f,0.f};

  int kend = (kw + 1) << 10;
  for (int k0 = kw << 10; k0 < kend; k0 += 64) {
    short8 kf[4][2];
    #pragma unroll
    for (int t=0;t<4;t++)
      #pragma unroll
      for (int hf=0;hf<2;hf++)
        kf[t][hf] = ldfrag_bf16(kb + (((k0>>4)+t)*2 + hf)*512 + lane*8);
    short8 vf[2][3];
    #pragma unroll
    for (int c0=0;c0<2;c0++)
      #pragma unroll
      for (int dt=0;dt<3;dt++)
        vf[c0][dt] = ldfrag_bf16(vb + (((k0>>6)*3 + dt)*2 + c0)*512 + lane*8);

    #pragma unroll
    for (int qt=0;qt<2;qt++) {
      #pragma unroll
      for (int t=0;t<4;t++) {
        floatx4 z = {0.f,0.f,0.f,0.f};
        floatx4 st = MFMA16(kf[t][0], qf[qt][0], MFMA16(kf[t][1], qf[qt][1], z));
        floatx4 p;
        #pragma unroll
        for (int r=0;r<4;r++) p[r] = __builtin_amdgcn_exp2f(st[r]);
        lv[qt] += p;                       // 4 independent accum chains
        uint2 pk2;
        pk2.x = cvt_pk_bf16(p[0], p[1]);
        pk2.y = cvt_pk_bf16(p[2], p[3]);
        *(uint2*)&lp[wv][lc][t*16 + quad*4] = pk2;
      }
      short8 pa0 = *(const short8*)&lp[wv][lc][quad*8];
      short8 pa1 = *(const short8*)&lp[wv][lc][32 + quad*8];
      #pragma unroll
      for (int dt=0;dt<3;dt++)
        acc[qt][dt] = MFMA16(pa1, vf[1][dt], MFMA16(pa0, vf[0][dt], acc[qt][dt]));
    }
  }
  float l0 = lv[0][0]+lv[0][1]+lv[0][2]+lv[0][3];
  float l1 = lv[1][0]+lv[1][1]+lv[1][2]+lv[1][3];
  __syncthreads();                        // all waves done with lp (cacc aliases it)
  if (kw) {                               // upper half: publish partials
    float* cb = &cacc[wq][lane][0];
    #pragma unroll
    for (int qt=0;qt<2;qt++)
      #pragma unroll
      for (int dt=0;dt<3;dt++)
        #pragma unroll
        for (int r=0;r<4;r++) cb[(qt*3+dt)*4 + r] = acc[qt][dt][r];
    cb[24] = l0; cb[25] = l1;
  }
  __syncthreads();
  if (kw) return;
  {                                       // lower half: combine
    const float* cb = &cacc[wq][lane][0];
    #pragma unroll
    for (int qt=0;qt<2;qt++)
      #pragma unroll
      for (int dt=0;dt<3;dt++)
        #pragma unroll
        for (int r=0;r<4;r++) acc[qt][dt][r] += cb[(qt*3+dt)*4 + r];
    l0 += cb[24]; l1 += cb[25];
  }
  float lq[2] = {l0, l1};
  #pragma unroll
  for (int qt=0;qt<2;qt++) {
    float s = lq[qt];
    s += __shfl_xor(s, 16, 64);
    s += __shfl_xor(s, 32, 64);
    float linv = 1.f/s;
    if (lane < 16) dinv[(size_t)bh*LQ + qw0 + qt*16 + lane] = linv;
    float li[4];
    #pragma unroll
    for (int r=0;r<4;r++) li[r] = __shfl(linv, quad*4 + r, 64);
    #pragma unroll
    for (int dt=0;dt<3;dt++)
      #pragma unroll
      for (int r=0;r<4;r++) {
        int mg = b*LQ + qw0 + qt*16 + quad*4 + r;
        int k  = h*HD_ + dt*16 + lc;
        size_t idx = (((size_t)(mg>>4)*(E_/32) + (k>>5))*64 + ((k>>3)&3)*16 + (mg&15))*8 + (k&7);
        ctxb[idx] = f2bf(acc[qt][dt][r]*li[r]);
      }
  }
}

// ---- attn_weights: 128q x 128k block tile, LDS-staged heads, dbuf -----------
#define AW_QSTR ((LQ/16)*1024)   // u16 elems per head in qfrag
#define AW_KSTR ((LK/16)*1024)   // u16 elems per head in kfrag

__global__ __launch_bounds__(512) void attn_weights_k(const u16* __restrict__ qfrag,
    const u16* __restrict__ kfrag, const float* __restrict__ dinv,
    float* __restrict__ aw) {
  __shared__ __align__(16) u16 sq[2][8192];   // [buf][tile(8)][half(2)][64][8]
  __shared__ __align__(16) u16 sk[2][8192];
  int tid = threadIdx.x;
  int lane = tid & 63, wv = tid >> 6;
  int lc = lane & 15, quad = lane >> 4;
  int xcd = blockIdx.x & 7, rest = blockIdx.x >> 3;
  int kx = rest & 15, g3 = rest >> 4;          // kx: k-block 0..15, g3: 0..3
  int y = xcd, b = g3;                         // q-band 0..7, batch 0..3
  int qblk = y*128, kblk = kx*128;
  int wq = wv & 1, wk = wv >> 1;               // wave tile: 64q x 32k
  int qw0 = qblk + wq*64;
  int k0  = kblk + wk*32;
  const u16* qb0 = qfrag + (size_t)(b*H_)*AW_QSTR + (qblk>>4)*1024;
  const u16* kb0 = kfrag + (size_t)(b*H_)*AW_KSTR + (kblk>>4)*1024;
  const float* dv0 = dinv + (size_t)(b*H_)*LQ + qw0;
  floatx4 acc[4][2];
  #pragma unroll
  for (int qt=0;qt<4;qt++)
    #pragma unroll
    for (int t=0;t<2;t++) acc[qt][t] = (floatx4){0.f,0.f,0.f,0.f};

  short8 gq[2], gk[2];
  #pragma unroll
  for (int i=0;i<2;i++) {
    gq[i] = *(const short8*)(qb0 + (size_t)(tid + i*512)*8);
    gk[i] = *(const short8*)(kb0 + (size_t)(tid + i*512)*8);
  }
  #pragma unroll
  for (int i=0;i<2;i++) {
    *(short8*)&sq[0][(tid + i*512)*8] = gq[i];
    *(short8*)&sk[0][(tid + i*512)*8] = gk[i];
  }
  __syncthreads();

  for (int h=0; h<H_; h++) {
    int cur = h & 1;
    if (h+1 < H_) {                      // issue next head's loads early
      const u16* qbn = qb0 + (size_t)(h+1)*AW_QSTR;
      const u16* kbn = kb0 + (size_t)(h+1)*AW_KSTR;
      #pragma unroll
      for (int i=0;i<2;i++) {
        gq[i] = *(const short8*)(qbn + (size_t)(tid + i*512)*8);
        gk[i] = *(const short8*)(kbn + (size_t)(tid + i*512)*8);
      }
    }
    float di[4];
    const float* dvh = dv0 + (size_t)h*LQ;
    #pragma unroll
    for (int qt=0;qt<4;qt++) di[qt] = dvh[qt*16 + lc];
    short8 kf[2][2];
    #pragma unroll
    for (int t=0;t<2;t++)
      #pragma unroll
      for (int hf=0;hf<2;hf++)
        kf[t][hf] = *(const short8*)&sk[cur][(((wk*2+t)*2+hf)*64 + lane)*8];
    #pragma unroll
    for (int qt=0;qt<4;qt++) {
      short8 qf0 = *(const short8*)&sq[cur][(((wq*4+qt)*2+0)*64 + lane)*8];
      short8 qf1 = *(const short8*)&sq[cur][(((wq*4+qt)*2+1)*64 + lane)*8];
      #pragma unroll
      for (int t=0;t<2;t++) {
        floatx4 z = {0.f,0.f,0.f,0.f};
        floatx4 st = MFMA16(kf[t][0], qf0, MFMA16(kf[t][1], qf1, z));
        #pragma unroll
        for (int r=0;r<4;r++)
          acc[qt][t][r] += __builtin_amdgcn_exp2f(st[r]) * di[qt];
      }
    }
    __syncthreads();                     // all waves done reading buf cur
    if (h+1 < H_) {
      int nxt = cur ^ 1;
      #pragma unroll
      for (int i=0;i<2;i++) {
        *(short8*)&sq[nxt][(tid + i*512)*8] = gq[i];
        *(short8*)&sk[nxt][(tid + i*512)*8] = gk[i];
      }
    }
    __syncthreads();                     // writes visible for next head
  }
  const float inv16 = 1.f/16.f;
  #pragma unroll
  for (int qt=0;qt<4;qt++)
    #pragma unroll
    for (int t=0;t<2;t++) {
      floatx4 v = acc[qt][t];
      v[0]*=inv16; v[1]*=inv16; v[2]*=inv16; v[3]*=inv16;
      *(floatx4*)&aw[((size_t)b*LQ + qw0 + qt*16 + lc)*LK + k0 + t*16 + quad*4] = v;
    }
}

// ---------------- fused gate + residual + layernorm --------------------------
__global__ __launch_bounds__(256) void final_ln_k(const float* __restrict__ query,
    const float* __restrict__ ao, const float* __restrict__ lng,
    const float* __restrict__ lnb, float* __restrict__ out) {
  int row = blockIdx.x, b = row >> 10, tid = threadIdx.x;
  float sf = out[SF_OFF + b];
  float gv = out[GV_OFF + b];
  float c1 = 2.f - gv, c2 = sf*gv;
  const float* q = query + (size_t)row*E_;
  const float* a = ao + (size_t)row*E_;
  float x[3], s1 = 0.f, s2 = 0.f;
  #pragma unroll
  for (int i=0;i<3;i++){ int j = tid + i*256; float v = q[j]*c1 + a[j]*c2; x[i]=v; s1+=v; s2+=v*v; }
  #pragma unroll
  for (int m=1;m<64;m<<=1){ s1 += __shfl_xor(s1,m,64); s2 += __shfl_xor(s2,m,64); }
  __shared__ float r1[4], r2[4];
  int wv = tid >> 6;
  if ((tid & 63) == 0){ r1[wv]=s1; r2[wv]=s2; }
  __syncthreads();
  s1 = r1[0]+r1[1]+r1[2]+r1[3];
  s2 = r2[0]+r2[1]+r2[2]+r2[3];
  float mu = s1*(1.f/E_);
  float var = s2*(1.f/E_) - mu*mu;
  float rs = rsqrtf(var + 1e-5f);
  #pragma unroll
  for (int i=0;i<3;i++){ int j = tid + i*256; out[(size_t)row*E_ + j] = (x[i]-mu)*rs*lng[j] + lnb[j]; }
}

extern "C" void kernel_launch(void* const* d_in, const int* in_sizes, int n_in,
                              void* d_out, int out_size, void* d_ws, size_t ws_size,
                              hipStream_t stream) {
  const float* query = (const float*)d_in[0];
  const float* key   = (const float*)d_in[1];
  const float* value = (const float*)d_in[2];
  const unsigned char* mask = (const unsigned char*)d_in[3];
  const float* Wp1 = (const float*)d_in[4];
  const float* bp1 = (const float*)d_in[5];
  const float* Wp2 = (const float*)d_in[6];
  const float* bp2 = (const float*)d_in[7];
  const float* Wp3 = (const float*)d_in[8];
  const float* bp3 = (const float*)d_in[9];
  const float* ipw = (const float*)d_in[10];
  const float* ipb = (const float*)d_in[11];
  const float* outw = (const float*)d_in[12];
  const float* outb = (const float*)d_in[13];
  const float* lng = (const float*)d_in[14];
  const float* lnb = (const float*)d_in[15];
  float* out = (float*)d_out;
  char* ws = (char*)d_ws;
  if (ws_size < WS_SMALL) return;
  bool full = (ws_size >= WS_FULL);
  float* pin  = (float*)(ws + WOFF_PIN);
  u16* qfrag  = (u16*)(ws + WOFF_QFRAG);
  u16* kfrag  = (u16*)(ws + WOFF_KFRAG);
  u16* vfrag  = (u16*)(ws + WOFF_VFRAG);
  u16* ctxb   = (u16*)(ws + WOFF_CTX);
  float* dinv = (float*)(ws + WOFF_DINV);
  float* h1   = (float*)(ws + WOFF_H1);
  float* h2   = (float*)(ws + WOFF_H2);
  u16* wbf    = (u16*)(ws + WOFF_WBF);
  u16* owbf   = (u16*)(ws + WOFF_OWBF);
  float* ao   = (float*)(ws + WOFF_AO);
  u16* vbf    = (u16*)(ws + WOFF_VBF);   // aliases ao (dead before ao written)
  u16* qbf    = (u16*)(ws + WOFF_QBF);
  u16* kbf    = (u16*)(ws + WOFF_KBF);

  hipMemsetAsync(ws, 0, WS_ZERO_BYTES, stream);  // pin + q/k frag padding
  maskpad_k<<<512, 256, 0, stream>>>(mask, qfrag, kfrag);
  pool_k<<<768, 192, 0, stream>>>(query, key, pin);
  mlp1_k<<<192, 256, 0, stream>>>(pin, Wp1, bp1, h1);
  mlp2_k<<<96, 256, 0, stream>>>(h1, Wp2, bp2, h2);
  mlp3_k<<<1, 256, 0, stream>>>(h2, Wp3, bp3, out);

  conv_frag_k<<<144, 256, 0, stream>>>(ipw, wbf);
  conv_frag_k<<<48, 256, 0, stream>>>(outw, owbf);
  const u16* wq = wbf;
  const u16* wk = wbf + (size_t)48*24*512;
  const u16* wvv = wbf + (size_t)96*24*512;
  if (full) {
    conv_frag_k<<<256, 256, 0, stream>>>(query, qbf);
    conv_frag_k<<<512, 256, 0, stream>>>(key, kbf);
    conv_frag_k<<<512, 256, 0, stream>>>(value, vbf);
    gemm_fm<1,true,10><<<dim3(12,32), 256, 0, stream>>>((const void*)qbf, wq, ipb, (void*)qfrag, SC2);
    gemm_fm<1,true,11><<<dim3(12,64), 256, 0, stream>>>((const void*)kbf, wk, ipb + E_, (void*)kfrag, 1.f);
    gemm_fm<2,true,11><<<dim3(12,64), 256, 0, stream>>>((const void*)vbf, wvv, ipb + 2*E_, (void*)vfrag, 1.f);
  } else {
    gemm_fm<1,false,10><<<dim3(12,32), 256, 0, stream>>>((const void*)query, wq, ipb, (void*)qfrag, SC2);
    gemm_fm<1,false,11><<<dim3(12,64), 256, 0, stream>>>((const void*)key, wk, ipb + E_, (void*)kfrag, 1.f);
    gemm_fm<2,false,11><<<dim3(12,64), 256, 0, stream>>>((const void*)value, wvv, ipb + 2*E_, (void*)vfrag, 1.f);
  }
  attn_fused_k<<<512, 512, 0, stream>>>(qfrag, kfrag, vfrag, dinv, ctxb);
  attn_weights_k<<<512, 512, 0, stream>>>(qfrag, kfrag, dinv, out + AW_OFF);
  gemm_fm<0,true,10><<<dim3(12,32), 256, 0, stream>>>((const void*)ctxb, owbf, outb, (void*)ao, 1.f);
  final_ln_k<<<4096, 256, 0, stream>>>(query, ao, lng, lnb, out);
}